// Round 23
// baseline (237.719 us; speedup 1.0000x reference)
//
#include <hip/hip_runtime.h>
#include <hip/hip_bf16.h>
#include <cstdint>
#include <cstddef>

#define DEV static __device__ __forceinline__

typedef __bf16 bf16x8 __attribute__((ext_vector_type(8)));
typedef float f32x4 __attribute__((ext_vector_type(4)));
typedef unsigned short u16;

static constexpr int BATCH = 2, SEQ = 2048, DM = 1024, NH = 16, DH = 64;
static constexpr int Kdim = 1024;
static constexpr int BS = BATCH * SEQ;  // 4096

DEV u16 f2b(float f) {  // f32 -> bf16 RNE
  uint32_t u = __builtin_bit_cast(uint32_t, f);
  u += 0x7FFFu + ((u >> 16) & 1u);
  return (u16)(u >> 16);
}

DEV void gload_lds16(const void* g, void* l) {
  __builtin_amdgcn_global_load_lds((const __attribute__((address_space(1))) void*)g,
                                   (__attribute__((address_space(3))) void*)l, 16, 0, 0);
}

DEV void plswap32(uint32_t& a, uint32_t& b) {
  asm("v_permlane32_swap_b32 %0, %1" : "+v"(a), "+v"(b));
}
DEV void plswap16(uint32_t& a, uint32_t& b) {
  asm("v_permlane16_swap_b32 %0, %1" : "+v"(a), "+v"(b));
}

// ---------------- fused cast f32 -> bf16 (x + 4 weights) + RoPE cos/sin table ----------------
__global__ __launch_bounds__(256) void cast_all(const float* __restrict__ x,
    const float* __restrict__ wq, const float* __restrict__ wk,
    const float* __restrict__ wv, const float* __restrict__ wo,
    const int* __restrict__ pos,
    u16* __restrict__ xb, u16* __restrict__ wqb, u16* __restrict__ wkb,
    u16* __restrict__ wvb, u16* __restrict__ wob, float2* __restrict__ tab) {
  const int NX = (BATCH * SEQ * DM) / 4;  // 2097152
  const int NW = (DM * DM) / 4;           // 262144 = 1<<18
  const int NT = SEQ * 32;                // 65536 table entries
  int i = blockIdx.x * blockDim.x + threadIdx.x;
  const int stride = gridDim.x * blockDim.x;
  for (; i < NX + 4 * NW + NT; i += stride) {
    if (i < NX + 4 * NW) {
      const float* src; u16* dst; int off;
      if (i < NX) { src = x; dst = xb; off = i; }
      else {
        const int j = i - NX, seg = j >> 18;
        off = j & (NW - 1);
        src = seg == 0 ? wq : seg == 1 ? wk : seg == 2 ? wv : wo;
        dst = seg == 0 ? wqb : seg == 1 ? wkb : seg == 2 ? wvb : wob;
      }
      float4 v = ((const float4*)src)[off];
      ushort4 o;
      o.x = f2b(v.x); o.y = f2b(v.y); o.z = f2b(v.z); o.w = f2b(v.w);
      ((ushort4*)dst)[off] = o;
    } else {
      const int t = i - NX - 4 * NW;
      const int s = t >> 5, j = t & 31;
      const float ang = (float)pos[s] * exp2f((float)j * -0.4152410118609203f);
      float sn, cs;
      sincosf(ang, &sn, &cs);
      tab[t] = make_float2(cs, sn);
    }
  }
}

// ---------------- generic GEMM core: 128x64, 2-buf, depth-1, counted vmcnt ----------------
template <bool OUTF32>
DEV void gemm_core64(const u16* __restrict__ A, const u16* __restrict__ Bm,
                     void* __restrict__ Cout, int ldC, int m0, int n0,
                     u16* __restrict__ As, u16* __restrict__ Bs) {
  const int tid = threadIdx.x;
  const int lane = tid & 63, wid = tid >> 6;
  const int wr = (wid >> 1) * 64, wc = (wid & 1) * 32;
  const int frow = lane & 15, fgrp = lane >> 4;
  constexpr int NK = Kdim / 32;
  f32x4 acc[4][2] = {};

  const int c0 = tid, c1 = tid + 256;
  const int ra0 = c0 >> 2, sa0 = (c0 & 3) ^ ((ra0 >> 1) & 3);
  const int ra1 = c1 >> 2, sa1 = (c1 & 3) ^ ((ra1 >> 1) & 3);
  const size_t gA0 = (size_t)(m0 + ra0) * Kdim + sa0 * 8;
  const size_t gA1 = (size_t)(m0 + ra1) * Kdim + sa1 * 8;
  const size_t gB0 = (size_t)(n0 + ra0) * Kdim + sa0 * 8;

#define GSTAGE(bufi, kofs)                                                      \
  do {                                                                          \
    gload_lds16(A + gA0 + (kofs), As + (bufi) * 4096 + wid * 512);              \
    gload_lds16(A + gA1 + (kofs), As + (bufi) * 4096 + wid * 512 + 2048);       \
    gload_lds16(Bm + gB0 + (kofs), Bs + (bufi) * 2048 + wid * 512);             \
  } while (0)

  GSTAGE(0, 0);
  for (int kt = 0; kt < NK; ++kt) {
    const int buf = kt & 1;
    if (kt + 1 < NK) {
      GSTAGE((kt + 1) & 1, (kt + 1) * 32);
      asm volatile("s_waitcnt vmcnt(3)" ::: "memory");
    } else {
      asm volatile("s_waitcnt vmcnt(0)" ::: "memory");
    }
    __builtin_amdgcn_s_barrier();

    bf16x8 af[4], bfr[2];
#pragma unroll
    for (int i = 0; i < 4; ++i) {
      const int ra = wr + i * 16 + frow;
      af[i] = *(const bf16x8*)((const char*)(As + buf * 4096) + ra * 64 +
                               ((fgrp ^ ((ra >> 1) & 3)) * 16));
    }
#pragma unroll
    for (int f = 0; f < 2; ++f) {
      const int rb = wc + f * 16 + frow;
      bfr[f] = *(const bf16x8*)((const char*)(Bs + buf * 2048) + rb * 64 +
                                ((fgrp ^ ((rb >> 1) & 3)) * 16));
    }
#pragma unroll
    for (int mi = 0; mi < 4; ++mi)
#pragma unroll
      for (int f = 0; f < 2; ++f)
        acc[mi][f] = __builtin_amdgcn_mfma_f32_16x16x32_bf16(af[mi], bfr[f], acc[mi][f], 0, 0, 0);

    __builtin_amdgcn_s_barrier();
  }
#undef GSTAGE

  const int colb = n0 + wc + frow;
  const int rowb = m0 + wr + fgrp * 4;
#pragma unroll
  for (int mi = 0; mi < 4; ++mi)
#pragma unroll
    for (int f = 0; f < 2; ++f)
#pragma unroll
      for (int r = 0; r < 4; ++r) {
        const int row = rowb + mi * 16 + r;
        const int col = colb + f * 16;
        const float v = acc[mi][f][r];
        if (OUTF32) ((float*)Cout)[(size_t)row * ldC + col] = v;
        else        ((u16*)Cout)[(size_t)row * ldC + col] = f2b(v);
      }
}

// ---------------- fused Q+K core (shares x A-panel; RoPE epilogue) ----------------
DEV void qk_core(const u16* __restrict__ xb, const u16* __restrict__ wq,
                 const u16* __restrict__ wk, u16* __restrict__ Qb, u16* __restrict__ Kb,
                 const float2* __restrict__ tab, int m0, int n0,
                 u16* __restrict__ As, u16* __restrict__ Bq, u16* __restrict__ Bk) {
  const int tid = threadIdx.x;
  const int lane = tid & 63, wid = tid >> 6;
  const int wr = (wid >> 1) * 64, wc = (wid & 1) * 32;
  const int frow = lane & 15, fgrp = lane >> 4;
  constexpr int NK = Kdim / 32;
  f32x4 accQ[4][2] = {}, accK[4][2] = {};

  const int c0 = tid, c1 = tid + 256;
  const int ra0 = c0 >> 2, sa0 = (c0 & 3) ^ ((ra0 >> 1) & 3);
  const int ra1 = c1 >> 2, sa1 = (c1 & 3) ^ ((ra1 >> 1) & 3);
  const size_t gA0 = (size_t)(m0 + ra0) * Kdim + sa0 * 8;
  const size_t gA1 = (size_t)(m0 + ra1) * Kdim + sa1 * 8;
  const size_t gB0 = (size_t)(n0 + ra0) * Kdim + sa0 * 8;

#define QKSTAGE(bufi, kofs)                                                     \
  do {                                                                          \
    gload_lds16(xb + gA0 + (kofs), As + (bufi) * 4096 + wid * 512);             \
    gload_lds16(xb + gA1 + (kofs), As + (bufi) * 4096 + wid * 512 + 2048);      \
    gload_lds16(wq + gB0 + (kofs), Bq + (bufi) * 2048 + wid * 512);             \
    gload_lds16(wk + gB0 + (kofs), Bk + (bufi) * 2048 + wid * 512);             \
  } while (0)

  QKSTAGE(0, 0);
  for (int kt = 0; kt < NK; ++kt) {
    const int buf = kt & 1;
    if (kt + 1 < NK) {
      QKSTAGE((kt + 1) & 1, (kt + 1) * 32);
      asm volatile("s_waitcnt vmcnt(4)" ::: "memory");
    } else {
      asm volatile("s_waitcnt vmcnt(0)" ::: "memory");
    }
    __builtin_amdgcn_s_barrier();

    bf16x8 af[4], bq[2], bk[2];
#pragma unroll
    for (int i = 0; i < 4; ++i) {
      const int ra = wr + i * 16 + frow;
      af[i] = *(const bf16x8*)((const char*)(As + buf * 4096) + ra * 64 +
                               ((fgrp ^ ((ra >> 1) & 3)) * 16));
    }
#pragma unroll
    for (int f2 = 0; f2 < 2; ++f2) {
      const int rb = wc + f2 * 16 + frow;
      const int off = rb * 64 + ((fgrp ^ ((rb >> 1) & 3)) * 16);
      bq[f2] = *(const bf16x8*)((const char*)(Bq + buf * 2048) + off);
      bk[f2] = *(const bf16x8*)((const char*)(Bk + buf * 2048) + off);
    }
#pragma unroll
    for (int mi = 0; mi < 4; ++mi)
#pragma unroll
      for (int f2 = 0; f2 < 2; ++f2) {
        accQ[mi][f2] = __builtin_amdgcn_mfma_f32_16x16x32_bf16(af[mi], bq[f2], accQ[mi][f2], 0, 0, 0);
        accK[mi][f2] = __builtin_amdgcn_mfma_f32_16x16x32_bf16(af[mi], bk[f2], accK[mi][f2], 0, 0, 0);
      }

    __builtin_amdgcn_s_barrier();
  }
#undef QKSTAGE

  const int colb = n0 + wc + frow;
  const int rowb = m0 + wr + fgrp * 4;
#pragma unroll
  for (int mi = 0; mi < 4; ++mi)
#pragma unroll
    for (int f2 = 0; f2 < 2; ++f2) {
      const int col = colb + f2 * 16;
      const int jj = (col & 63) >> 1;
      const int odd = col & 1;
#pragma unroll
      for (int r = 0; r < 4; ++r) {
        const int row = rowb + mi * 16 + r;
        const float2 cs_ = tab[(row & (SEQ - 1)) * 32 + jj];
        const float qv = accQ[mi][f2][r];
        const float qp = __shfl_xor(qv, 1);
        const float kv = accK[mi][f2][r];
        const float kp = __shfl_xor(kv, 1);
        float oq = odd ? fmaf(cs_.y, qp, cs_.x * qv) : fmaf(cs_.x, qv, -cs_.y * qp);
        float ok = odd ? fmaf(cs_.y, kp, cs_.x * kv) : fmaf(cs_.x, kv, -cs_.y * kp);
        oq *= 0.18033688011112043f;  // (1/8)*log2(e), folded into Q
        Qb[(size_t)row * DM + col] = f2b(oq);
        Kb[(size_t)row * DM + col] = f2b(ok);
      }
    }
}

// ---------------- ALL projections in ONE launch (tail overlap) ----------------
__global__ __launch_bounds__(256) void gemm_proj(const u16* __restrict__ xb,
    const u16* __restrict__ wq, const u16* __restrict__ wk, const u16* __restrict__ wv,
    u16* __restrict__ Qb, u16* __restrict__ Kb, u16* __restrict__ Vtb,
    const float2* __restrict__ tab) {
  __shared__ u16 As[2][4096], B1[2][2048], B2[2][2048];
  const int g = blockIdx.x;
  if (g < 512) {
    const int xcd = g & 7, j = g >> 3;
    const int m0 = (xcd * 4 + (j >> 4)) * 128, n0 = (j & 15) * 64;
    qk_core(xb, wq, wk, Qb, Kb, tab, m0, n0, &As[0][0], &B1[0][0], &B2[0][0]);
  } else {
    const int f = g - 512;
    const int xcd = f & 7, j = f >> 3;
    const int m0 = xcd * 128, n0 = j * 64;
    gemm_core64<false>(wv, xb, Vtb, BS, m0, n0, &As[0][0], &B1[0][0]);
  }
}

__global__ __launch_bounds__(256) void gemm_o(const u16* __restrict__ attb,
                                              const u16* __restrict__ wob,
                                              float* __restrict__ out) {
  __shared__ u16 As[2][4096], Bs[2][2048];
  const int f = blockIdx.x;                  // 0..511
  const int xcd = f & 7, k = f >> 3;
  const int grp = xcd * 8 + (k >> 3);
  const int m0 = (grp >> 1) * 128;
  const int n0 = ((grp & 1) * 8 + (k & 7)) * 64;
  gemm_core64<true>(attb, wob, out, DM, m0, n0, &As[0][0], &Bs[0][0]);
}

// ---------------- fused causal flash attention ----------------
// 4-wave kv-quarter structure, SINGLE-buffered K/V (R20 algorithm, validated
// correct), natural register budget this time: __launch_bounds__(256) only —
// R20's (256,4) bound forced 64 VGPR and spilled everything (641MB scratch).
// LDS 40KB => 4 blocks/CU at VGPR<=128 (R22 measured 124). Load latency is
// exposed within a block, hidden across the 4 co-resident blocks.
// LDS map (compute): [0,16K) K | [16K,32K) V^T | [32K,40K) Q.
// Merge (per 32-row half, padded stride 68): Of = 4 x 8704B, Ld at 34816.
__global__ __launch_bounds__(256) void attn_kernel(const u16* __restrict__ Qb,
                                                   const u16* __restrict__ Kb,
                                                   const u16* __restrict__ Vtb,
                                                   u16* __restrict__ attb) {
  __shared__ __align__(16) unsigned char SM[40960];
  float* Of = (float*)SM;
  float* Ld = (float*)(SM + 34816);

  const int tid = threadIdx.x, lane = tid & 63, wid = tid >> 6;
  const int flat = (int)blockIdx.x + 16 * (int)blockIdx.y;  // 0..511
  const int orig = (flat & 7) * 64 + (flat >> 3);           // bijective XCD swizzle
  const int xq = orig & 15;
  const int bh = orig >> 4;
  const int b = bh >> 4, h = bh & 15;
  const size_t base_bh = ((size_t)b * SEQ) * DM + h * DH;
  const int frow = lane & 15, fgrp = lane >> 4;
  const int w32 = wid * 32;
  const int swz = (frow & 7) << 4;

  const u16* Ksrcs[4];
  const u16* Vsrcs[4];
#pragma unroll
  for (int i = 0; i < 4; ++i) {
    const int c = tid + i * 256;
    const int rk = c >> 3, s8 = (c & 7) ^ (rk & 7);
    Ksrcs[i] = Kb + base_bh + (size_t)rk * DM + s8 * 8;
    const int rv = c >> 4, s16 = (c & 15) ^ (rv & 7);
    Vsrcs[i] = Vtb + (size_t)(h * DH + rv) * BS + (size_t)b * SEQ + s16 * 8;
  }
  const int cq0 = tid, cq1 = tid + 256;
  const int rq0 = cq0 >> 3, sq0 = (cq0 & 7) ^ (rq0 & 7);
  const int rq1 = cq1 >> 3, sq1 = (cq1 & 7) ^ (rq1 & 7);

#pragma unroll 1
  for (int phase = 0; phase < 2; ++phase) {
    const int qt = phase ? xq : 31 - xq;
    const int q0 = qt * 64;
    const int nkv = (qt >> 1) + 1;

    // prologue: stage Q + K/V tile 0 (single buffer)
    gload_lds16(Qb + base_bh + (size_t)(q0 + rq0) * DM + sq0 * 8, (char*)SM + 32768 + tid * 16);
    gload_lds16(Qb + base_bh + (size_t)(q0 + rq1) * DM + sq1 * 8, (char*)SM + 36864 + tid * 16);
#pragma unroll
    for (int i = 0; i < 4; ++i) {
      gload_lds16(Ksrcs[i], (char*)SM + wid * 1024 + i * 4096);
      gload_lds16(Vsrcs[i], (char*)SM + 16384 + wid * 1024 + i * 4096);
    }
    __syncthreads();

    bf16x8 qf[4][2];
#pragma unroll
    for (int qs = 0; qs < 4; ++qs)
#pragma unroll
      for (int ks = 0; ks < 2; ++ks) {
        const int byte = ((qs * 16 + frow) * 128 + ks * 64 + fgrp * 16) ^ swz;
        qf[qs][ks] = *(const bf16x8*)((const char*)SM + 32768 + byte);
      }

    f32x4 accO[4][4] = {};
    float l_lane[4] = {0.f, 0.f, 0.f, 0.f};

    const char* Kc = (const char*)SM;
    const char* Vc = (const char*)SM + 16384;

    for (int kt = 0; kt < nkv; ++kt) {
      f32x4 sc[4][2] = {};
      __builtin_amdgcn_s_setprio(1);
#pragma unroll
      for (int tc = 0; tc < 2; ++tc)
#pragma unroll
        for (int ks = 0; ks < 2; ++ks) {
          const int byte = ((w32 + tc * 16 + frow) * 128 + ks * 64 + fgrp * 16) ^ swz;
          const bf16x8 kf = *(const bf16x8*)(Kc + byte);
#pragma unroll
          for (int qs = 0; qs < 4; ++qs)
            sc[qs][tc] = __builtin_amdgcn_mfma_f32_16x16x32_bf16(kf, qf[qs][ks], sc[qs][tc], 0, 0, 0);
        }
      __builtin_amdgcn_s_setprio(0);

      if (kt == nkv - 1) {
        const int kv0 = kt * 128;
#pragma unroll
        for (int qs = 0; qs < 4; ++qs)
#pragma unroll
          for (int tc = 0; tc < 2; ++tc)
#pragma unroll
            for (int r = 0; r < 4; ++r)
              if (kv0 + w32 + tc * 16 + fgrp * 4 + r > q0 + qs * 16 + frow)
                sc[qs][tc][r] = -1e30f;
      }

      bf16x8 pf[4];
#pragma unroll
      for (int qs = 0; qs < 4; ++qs) {
        const float p00 = exp2f(sc[qs][0][0]), p01 = exp2f(sc[qs][0][1]);
        const float p02 = exp2f(sc[qs][0][2]), p03 = exp2f(sc[qs][0][3]);
        const float p10 = exp2f(sc[qs][1][0]), p11 = exp2f(sc[qs][1][1]);
        const float p12 = exp2f(sc[qs][1][2]), p13 = exp2f(sc[qs][1][3]);
        l_lane[qs] += ((p00 + p01) + (p02 + p03)) + ((p10 + p11) + (p12 + p13));
        union { __bf16 bb[2]; uint32_t uu; } c00, c01, c10, c11;
        c00.bb[0] = (__bf16)p00; c00.bb[1] = (__bf16)p01;
        c01.bb[0] = (__bf16)p02; c01.bb[1] = (__bf16)p03;
        c10.bb[0] = (__bf16)p10; c10.bb[1] = (__bf16)p11;
        c11.bb[0] = (__bf16)p12; c11.bb[1] = (__bf16)p13;
        uint32_t a0 = c00.uu, a1 = c01.uu, b0 = c10.uu, b1 = c11.uu;
        plswap32(a0, b0); plswap16(a0, b0);
        plswap32(a1, b1); plswap16(a1, b1);
        union { uint32_t w[4]; bf16x8 v; } pk;
        pk.w[0] = a0; pk.w[1] = a1; pk.w[2] = b0; pk.w[3] = b1;
        pf[qs] = pk.v;
      }

      __builtin_amdgcn_s_setprio(1);
#pragma unroll
      for (int te = 0; te < 4; ++te) {
        const int byte = ((te * 16 + frow) * 256 + wid * 64 + fgrp * 16) ^ swz;
        const bf16x8 vf = *(const bf16x8*)(Vc + byte);
#pragma unroll
        for (int qs = 0; qs < 4; ++qs)
          accO[qs][te] = __builtin_amdgcn_mfma_f32_16x16x32_bf16(pf[qs], vf, accO[qs][te], 0, 0, 0);
      }
      __builtin_amdgcn_s_setprio(0);
      __syncthreads();  // all waves done reading tile kt

      if (kt + 1 < nkv) {  // stage tile kt+1 into the same buffer
        const size_t kvn = (size_t)(kt + 1) * 128;
#pragma unroll
        for (int i = 0; i < 4; ++i) {
          gload_lds16(Ksrcs[i] + kvn * DM, (char*)SM + wid * 1024 + i * 4096);
          gload_lds16(Vsrcs[i] + kvn, (char*)SM + 16384 + wid * 1024 + i * 4096);
        }
        __syncthreads();  // drains vmcnt; tile kt+1 resident
      }
    }

    // ---- cross-wave merge in two 32-row halves (padded stride 68) ----
#pragma unroll
    for (int qs = 0; qs < 4; ++qs) {
      l_lane[qs] += __shfl_xor(l_lane[qs], 16);
      l_lane[qs] += __shfl_xor(l_lane[qs], 32);
    }
#pragma unroll 1
    for (int hh = 0; hh < 2; ++hh) {
      float* myOf = Of + wid * 2176;  // 32 rows x 68 words per wave
#pragma unroll
      for (int q2 = 0; q2 < 2; ++q2) {
        const int qs = hh * 2 + q2;
#pragma unroll
        for (int te = 0; te < 4; ++te)
#pragma unroll
          for (int r = 0; r < 4; ++r)
            myOf[(q2 * 16 + fgrp * 4 + r) * 68 + te * 16 + frow] = accO[qs][te][r];
      }
      if (fgrp == 0) {
#pragma unroll
        for (int q2 = 0; q2 < 2; ++q2)
          Ld[wid * 32 + q2 * 16 + frow] = l_lane[hh * 2 + q2];
      }
      __syncthreads();

      // assemble 32 rows of this half: wave w owns rows [w*8, w*8+8)
#pragma unroll
      for (int ii = 0; ii < 2; ++ii) {
        const int qll = wid * 8 + fgrp * 2 + ii;  // 0..31 within half
        f32x4 s = {};
        float lq = 0.f;
#pragma unroll
        for (int wv = 0; wv < 4; ++wv) {
          s += *(const f32x4*)(Of + wv * 2176 + qll * 68 + frow * 4);
          lq += Ld[wv * 32 + qll];
        }
        const float inv = 1.0f / lq;
        ushort4 o;
        o.x = f2b(s[0] * inv); o.y = f2b(s[1] * inv);
        o.z = f2b(s[2] * inv); o.w = f2b(s[3] * inv);
        *(ushort4*)(attb + base_bh + (size_t)(q0 + hh * 32 + qll) * DM + frow * 4) = o;
      }
      __syncthreads();  // before next half / next phase overwrites Of
    }
  }
}

extern "C" void kernel_launch(void* const* d_in, const int* in_sizes, int n_in,
                              void* d_out, int out_size, void* d_ws, size_t ws_size,
                              hipStream_t stream) {
  const float* x  = (const float*)d_in[0];
  const float* wq = (const float*)d_in[1];
  const float* wk = (const float*)d_in[2];
  const float* wv = (const float*)d_in[3];
  const float* wo = (const float*)d_in[4];
  const int* pos  = (const int*)d_in[5];
  float* out = (float*)d_out;
  (void)in_sizes; (void)n_in; (void)out_size; (void)ws_size;

  char* ws = (char*)d_ws;
  const size_t MB = 1024 * 1024;
  u16* xb   = (u16*)(ws);
  u16* wqb  = (u16*)(ws + 8 * MB);
  u16* wkb  = (u16*)(ws + 10 * MB);
  u16* wvb  = (u16*)(ws + 12 * MB);
  u16* wob  = (u16*)(ws + 14 * MB);
  u16* Qb   = (u16*)(ws + 16 * MB);
  u16* Kb   = (u16*)(ws + 24 * MB);
  u16* Vtb  = (u16*)(ws + 32 * MB);   // V^T: [1024][4096]
  u16* attb = (u16*)(ws + 40 * MB);
  float2* tab = (float2*)(ws + 40 * MB);  // aliases attb (dead by attn time)

  cast_all<<<2048, 256, 0, stream>>>(x, wq, wk, wv, wo, pos, xb, wqb, wkb, wvb, wob, tab);
  gemm_proj<<<1024, 256, 0, stream>>>(xb, wqb, wkb, wvb, Qb, Kb, Vtb, tab);
  attn_kernel<<<dim3(16, 32), 256, 0, stream>>>(Qb, Kb, Vtb, attb);
  gemm_o<<<512, 256, 0, stream>>>(attb, wob, out);
}

// Round 24
// 111.780 us; speedup vs baseline: 2.1267x; 2.1267x over previous
//
#include <hip/hip_runtime.h>
#include <hip/hip_bf16.h>
#include <cstdint>
#include <cstddef>

#define DEV static __device__ __forceinline__

typedef __bf16 bf16x8 __attribute__((ext_vector_type(8)));
typedef float f32x4 __attribute__((ext_vector_type(4)));
typedef unsigned short u16;

static constexpr int BATCH = 2, SEQ = 2048, DM = 1024, NH = 16, DH = 64;
static constexpr int Kdim = 1024;
static constexpr int BS = BATCH * SEQ;  // 4096

DEV u16 f2b(float f) {  // f32 -> bf16 RNE
  uint32_t u = __builtin_bit_cast(uint32_t, f);
  u += 0x7FFFu + ((u >> 16) & 1u);
  return (u16)(u >> 16);
}

DEV void gload_lds16(const void* g, void* l) {
  __builtin_amdgcn_global_load_lds((const __attribute__((address_space(1))) void*)g,
                                   (__attribute__((address_space(3))) void*)l, 16, 0, 0);
}

DEV void plswap32(uint32_t& a, uint32_t& b) {
  asm("v_permlane32_swap_b32 %0, %1" : "+v"(a), "+v"(b));
}
DEV void plswap16(uint32_t& a, uint32_t& b) {
  asm("v_permlane16_swap_b32 %0, %1" : "+v"(a), "+v"(b));
}

// ---------------- fused cast f32 -> bf16 (x + 4 weights) + RoPE cos/sin table ----------------
__global__ __launch_bounds__(256) void cast_all(const float* __restrict__ x,
    const float* __restrict__ wq, const float* __restrict__ wk,
    const float* __restrict__ wv, const float* __restrict__ wo,
    const int* __restrict__ pos,
    u16* __restrict__ xb, u16* __restrict__ wqb, u16* __restrict__ wkb,
    u16* __restrict__ wvb, u16* __restrict__ wob, float2* __restrict__ tab) {
  const int NX = (BATCH * SEQ * DM) / 4;  // 2097152
  const int NW = (DM * DM) / 4;           // 262144 = 1<<18
  const int NT = SEQ * 32;                // 65536 table entries
  int i = blockIdx.x * blockDim.x + threadIdx.x;
  const int stride = gridDim.x * blockDim.x;
  for (; i < NX + 4 * NW + NT; i += stride) {
    if (i < NX + 4 * NW) {
      const float* src; u16* dst; int off;
      if (i < NX) { src = x; dst = xb; off = i; }
      else {
        const int j = i - NX, seg = j >> 18;
        off = j & (NW - 1);
        src = seg == 0 ? wq : seg == 1 ? wk : seg == 2 ? wv : wo;
        dst = seg == 0 ? wqb : seg == 1 ? wkb : seg == 2 ? wvb : wob;
      }
      float4 v = ((const float4*)src)[off];
      ushort4 o;
      o.x = f2b(v.x); o.y = f2b(v.y); o.z = f2b(v.z); o.w = f2b(v.w);
      ((ushort4*)dst)[off] = o;
    } else {
      const int t = i - NX - 4 * NW;
      const int s = t >> 5, j = t & 31;
      const float ang = (float)pos[s] * exp2f((float)j * -0.4152410118609203f);
      float sn, cs;
      sincosf(ang, &sn, &cs);
      tab[t] = make_float2(cs, sn);
    }
  }
}

// ---------------- generic GEMM core: 128x64, 2-buf, depth-1, counted vmcnt ----------------
template <bool OUTF32>
DEV void gemm_core64(const u16* __restrict__ A, const u16* __restrict__ Bm,
                     void* __restrict__ Cout, int ldC, int m0, int n0,
                     u16* __restrict__ As, u16* __restrict__ Bs) {
  const int tid = threadIdx.x;
  const int lane = tid & 63, wid = tid >> 6;
  const int wr = (wid >> 1) * 64, wc = (wid & 1) * 32;
  const int frow = lane & 15, fgrp = lane >> 4;
  constexpr int NK = Kdim / 32;
  f32x4 acc[4][2] = {};

  const int c0 = tid, c1 = tid + 256;
  const int ra0 = c0 >> 2, sa0 = (c0 & 3) ^ ((ra0 >> 1) & 3);
  const int ra1 = c1 >> 2, sa1 = (c1 & 3) ^ ((ra1 >> 1) & 3);
  const size_t gA0 = (size_t)(m0 + ra0) * Kdim + sa0 * 8;
  const size_t gA1 = (size_t)(m0 + ra1) * Kdim + sa1 * 8;
  const size_t gB0 = (size_t)(n0 + ra0) * Kdim + sa0 * 8;

#define GSTAGE(bufi, kofs)                                                      \
  do {                                                                          \
    gload_lds16(A + gA0 + (kofs), As + (bufi) * 4096 + wid * 512);              \
    gload_lds16(A + gA1 + (kofs), As + (bufi) * 4096 + wid * 512 + 2048);       \
    gload_lds16(Bm + gB0 + (kofs), Bs + (bufi) * 2048 + wid * 512);             \
  } while (0)

  GSTAGE(0, 0);
  for (int kt = 0; kt < NK; ++kt) {
    const int buf = kt & 1;
    if (kt + 1 < NK) {
      GSTAGE((kt + 1) & 1, (kt + 1) * 32);
      asm volatile("s_waitcnt vmcnt(3)" ::: "memory");
    } else {
      asm volatile("s_waitcnt vmcnt(0)" ::: "memory");
    }
    __builtin_amdgcn_s_barrier();

    bf16x8 af[4], bfr[2];
#pragma unroll
    for (int i = 0; i < 4; ++i) {
      const int ra = wr + i * 16 + frow;
      af[i] = *(const bf16x8*)((const char*)(As + buf * 4096) + ra * 64 +
                               ((fgrp ^ ((ra >> 1) & 3)) * 16));
    }
#pragma unroll
    for (int f = 0; f < 2; ++f) {
      const int rb = wc + f * 16 + frow;
      bfr[f] = *(const bf16x8*)((const char*)(Bs + buf * 2048) + rb * 64 +
                                ((fgrp ^ ((rb >> 1) & 3)) * 16));
    }
#pragma unroll
    for (int mi = 0; mi < 4; ++mi)
#pragma unroll
      for (int f = 0; f < 2; ++f)
        acc[mi][f] = __builtin_amdgcn_mfma_f32_16x16x32_bf16(af[mi], bfr[f], acc[mi][f], 0, 0, 0);

    __builtin_amdgcn_s_barrier();
  }
#undef GSTAGE

  const int colb = n0 + wc + frow;
  const int rowb = m0 + wr + fgrp * 4;
#pragma unroll
  for (int mi = 0; mi < 4; ++mi)
#pragma unroll
    for (int f = 0; f < 2; ++f)
#pragma unroll
      for (int r = 0; r < 4; ++r) {
        const int row = rowb + mi * 16 + r;
        const int col = colb + f * 16;
        const float v = acc[mi][f][r];
        if (OUTF32) ((float*)Cout)[(size_t)row * ldC + col] = v;
        else        ((u16*)Cout)[(size_t)row * ldC + col] = f2b(v);
      }
}

// ---------------- fused Q+K core (shares x A-panel; RoPE epilogue) ----------------
DEV void qk_core(const u16* __restrict__ xb, const u16* __restrict__ wq,
                 const u16* __restrict__ wk, u16* __restrict__ Qb, u16* __restrict__ Kb,
                 const float2* __restrict__ tab, int m0, int n0,
                 u16* __restrict__ As, u16* __restrict__ Bq, u16* __restrict__ Bk) {
  const int tid = threadIdx.x;
  const int lane = tid & 63, wid = tid >> 6;
  const int wr = (wid >> 1) * 64, wc = (wid & 1) * 32;
  const int frow = lane & 15, fgrp = lane >> 4;
  constexpr int NK = Kdim / 32;
  f32x4 accQ[4][2] = {}, accK[4][2] = {};

  const int c0 = tid, c1 = tid + 256;
  const int ra0 = c0 >> 2, sa0 = (c0 & 3) ^ ((ra0 >> 1) & 3);
  const int ra1 = c1 >> 2, sa1 = (c1 & 3) ^ ((ra1 >> 1) & 3);
  const size_t gA0 = (size_t)(m0 + ra0) * Kdim + sa0 * 8;
  const size_t gA1 = (size_t)(m0 + ra1) * Kdim + sa1 * 8;
  const size_t gB0 = (size_t)(n0 + ra0) * Kdim + sa0 * 8;

#define QKSTAGE(bufi, kofs)                                                     \
  do {                                                                          \
    gload_lds16(xb + gA0 + (kofs), As + (bufi) * 4096 + wid * 512);             \
    gload_lds16(xb + gA1 + (kofs), As + (bufi) * 4096 + wid * 512 + 2048);      \
    gload_lds16(wq + gB0 + (kofs), Bq + (bufi) * 2048 + wid * 512);             \
    gload_lds16(wk + gB0 + (kofs), Bk + (bufi) * 2048 + wid * 512);             \
  } while (0)

  QKSTAGE(0, 0);
  for (int kt = 0; kt < NK; ++kt) {
    const int buf = kt & 1;
    if (kt + 1 < NK) {
      QKSTAGE((kt + 1) & 1, (kt + 1) * 32);
      asm volatile("s_waitcnt vmcnt(4)" ::: "memory");
    } else {
      asm volatile("s_waitcnt vmcnt(0)" ::: "memory");
    }
    __builtin_amdgcn_s_barrier();

    bf16x8 af[4], bq[2], bk[2];
#pragma unroll
    for (int i = 0; i < 4; ++i) {
      const int ra = wr + i * 16 + frow;
      af[i] = *(const bf16x8*)((const char*)(As + buf * 4096) + ra * 64 +
                               ((fgrp ^ ((ra >> 1) & 3)) * 16));
    }
#pragma unroll
    for (int f2 = 0; f2 < 2; ++f2) {
      const int rb = wc + f2 * 16 + frow;
      const int off = rb * 64 + ((fgrp ^ ((rb >> 1) & 3)) * 16);
      bq[f2] = *(const bf16x8*)((const char*)(Bq + buf * 2048) + off);
      bk[f2] = *(const bf16x8*)((const char*)(Bk + buf * 2048) + off);
    }
#pragma unroll
    for (int mi = 0; mi < 4; ++mi)
#pragma unroll
      for (int f2 = 0; f2 < 2; ++f2) {
        accQ[mi][f2] = __builtin_amdgcn_mfma_f32_16x16x32_bf16(af[mi], bq[f2], accQ[mi][f2], 0, 0, 0);
        accK[mi][f2] = __builtin_amdgcn_mfma_f32_16x16x32_bf16(af[mi], bk[f2], accK[mi][f2], 0, 0, 0);
      }

    __builtin_amdgcn_s_barrier();
  }
#undef QKSTAGE

  const int colb = n0 + wc + frow;
  const int rowb = m0 + wr + fgrp * 4;
#pragma unroll
  for (int mi = 0; mi < 4; ++mi)
#pragma unroll
    for (int f2 = 0; f2 < 2; ++f2) {
      const int col = colb + f2 * 16;
      const int jj = (col & 63) >> 1;
      const int odd = col & 1;
#pragma unroll
      for (int r = 0; r < 4; ++r) {
        const int row = rowb + mi * 16 + r;
        const float2 cs_ = tab[(row & (SEQ - 1)) * 32 + jj];
        const float qv = accQ[mi][f2][r];
        const float qp = __shfl_xor(qv, 1);
        const float kv = accK[mi][f2][r];
        const float kp = __shfl_xor(kv, 1);
        float oq = odd ? fmaf(cs_.y, qp, cs_.x * qv) : fmaf(cs_.x, qv, -cs_.y * qp);
        float ok = odd ? fmaf(cs_.y, kp, cs_.x * kv) : fmaf(cs_.x, kv, -cs_.y * kp);
        oq *= 0.18033688011112043f;  // (1/8)*log2(e), folded into Q
        Qb[(size_t)row * DM + col] = f2b(oq);
        Kb[(size_t)row * DM + col] = f2b(ok);
      }
    }
}

// ---------------- ALL projections in ONE launch (tail overlap) ----------------
// g < 512: fused Q+K tile; g >= 512: V^T tile. XCD locality preserved (g&7).
__global__ __launch_bounds__(256) void gemm_proj(const u16* __restrict__ xb,
    const u16* __restrict__ wq, const u16* __restrict__ wk, const u16* __restrict__ wv,
    u16* __restrict__ Qb, u16* __restrict__ Kb, u16* __restrict__ Vtb,
    const float2* __restrict__ tab) {
  __shared__ u16 As[2][4096], B1[2][2048], B2[2][2048];
  const int g = blockIdx.x;
  if (g < 512) {
    const int xcd = g & 7, j = g >> 3;
    const int m0 = (xcd * 4 + (j >> 4)) * 128, n0 = (j & 15) * 64;
    qk_core(xb, wq, wk, Qb, Kb, tab, m0, n0, &As[0][0], &B1[0][0], &B2[0][0]);
  } else {
    const int f = g - 512;
    const int xcd = f & 7, j = f >> 3;
    const int m0 = xcd * 128, n0 = j * 64;
    gemm_core64<false>(wv, xb, Vtb, BS, m0, n0, &As[0][0], &B1[0][0]);
  }
}

__global__ __launch_bounds__(256) void gemm_o(const u16* __restrict__ attb,
                                              const u16* __restrict__ wob,
                                              float* __restrict__ out) {
  __shared__ u16 As[2][4096], Bs[2][2048];
  const int f = blockIdx.x;                  // 0..511
  const int xcd = f & 7, k = f >> 3;
  const int grp = xcd * 8 + (k >> 3);
  const int m0 = (grp >> 1) * 128;
  const int n0 = ((grp & 1) * 8 + (k & 7)) * 64;
  gemm_core64<true>(attb, wob, out, DM, m0, n0, &As[0][0], &Bs[0][0]);
}

// ---------------- fused causal flash attention (4-wave, measured best: R22) ----------------
// Merge-phase Of row stride padded 64 -> 68 words: writes 2-way (free),
// f32x4 reads ~4-way (was 4-way/8-way). Of = 4 x 17408B = 69632B overlapping
// the dead Qs region during merge; Ld at byte 69632.
__global__ __launch_bounds__(256, 2) void attn_kernel(const u16* __restrict__ Qb,
                                                      const u16* __restrict__ Kb,
                                                      const u16* __restrict__ Vtb,
                                                      u16* __restrict__ attb) {
  __shared__ __align__(16) unsigned char SM[73728];
  u16* Qs = (u16*)(SM + 65536);
  float* Of = (float*)SM;
  float* Ld = (float*)(SM + 69632);

  const int tid = threadIdx.x, lane = tid & 63, wid = tid >> 6;
  const int flat = (int)blockIdx.x + 16 * (int)blockIdx.y;  // 0..511
  const int orig = (flat & 7) * 64 + (flat >> 3);           // bijective XCD swizzle
  const int xq = orig & 15;
  const int bh = orig >> 4;
  const int b = bh >> 4, h = bh & 15;
  const size_t base_bh = ((size_t)b * SEQ) * DM + h * DH;
  const int frow = lane & 15, fgrp = lane >> 4;
  const int w32 = wid * 32;
  const int swz = (frow & 7) << 4;

  const u16* Ksrcs[4];
  const u16* Vsrcs[4];
#pragma unroll
  for (int i = 0; i < 4; ++i) {
    const int c = tid + i * 256;
    const int rk = c >> 3, s8 = (c & 7) ^ (rk & 7);
    Ksrcs[i] = Kb + base_bh + (size_t)rk * DM + s8 * 8;
    const int rv = c >> 4, s16 = (c & 15) ^ (rv & 7);
    Vsrcs[i] = Vtb + (size_t)(h * DH + rv) * BS + (size_t)b * SEQ + s16 * 8;
  }
  const int cq0 = tid, cq1 = tid + 256;
  const int rq0 = cq0 >> 3, sq0 = (cq0 & 7) ^ (rq0 & 7);
  const int rq1 = cq1 >> 3, sq1 = (cq1 & 7) ^ (rq1 & 7);

#pragma unroll 1
  for (int phase = 0; phase < 2; ++phase) {
    const int qt = phase ? xq : 31 - xq;
    const int q0 = qt * 64;
    const int nkv = (qt >> 1) + 1;

    gload_lds16(Qb + base_bh + (size_t)(q0 + rq0) * DM + sq0 * 8, (char*)SM + 65536 + tid * 16);
    gload_lds16(Qb + base_bh + (size_t)(q0 + rq1) * DM + sq1 * 8, (char*)SM + 69632 + tid * 16);
#pragma unroll
    for (int i = 0; i < 4; ++i) {
      gload_lds16(Ksrcs[i], (char*)SM + wid * 1024 + i * 4096);
      gload_lds16(Vsrcs[i], (char*)SM + 32768 + wid * 1024 + i * 4096);
    }
    __syncthreads();

    bf16x8 qf[4][2];
#pragma unroll
    for (int qs = 0; qs < 4; ++qs)
#pragma unroll
      for (int ks = 0; ks < 2; ++ks) {
        const int byte = ((qs * 16 + frow) * 128 + ks * 64 + fgrp * 16) ^ swz;
        qf[qs][ks] = *(const bf16x8*)((const char*)Qs + byte);
      }

    f32x4 accO[4][4] = {};
    float l_lane[4] = {0.f, 0.f, 0.f, 0.f};

    // strength-reduced prefetch pointers (advance by constant stride per iter)
    const u16* Kp[4];
    const u16* Vp[4];
#pragma unroll
    for (int i = 0; i < 4; ++i) { Kp[i] = Ksrcs[i] + (size_t)128 * DM; Vp[i] = Vsrcs[i] + 128; }

    for (int kt = 0; kt < nkv; ++kt) {
      const char* Kc = (const char*)SM + (kt & 1) * 16384;
      const char* Vc = (const char*)SM + 32768 + (kt & 1) * 16384;
      if (kt + 1 < nkv) {
        const int nb = (kt + 1) & 1;
#pragma unroll
        for (int i = 0; i < 4; ++i) {
          gload_lds16(Kp[i], (char*)SM + nb * 16384 + wid * 1024 + i * 4096);
          gload_lds16(Vp[i], (char*)SM + 32768 + nb * 16384 + wid * 1024 + i * 4096);
          Kp[i] += (size_t)128 * DM;
          Vp[i] += 128;
        }
      }

      f32x4 sc[4][2] = {};
      __builtin_amdgcn_s_setprio(1);
#pragma unroll
      for (int tc = 0; tc < 2; ++tc)
#pragma unroll
        for (int ks = 0; ks < 2; ++ks) {
          const int byte = ((w32 + tc * 16 + frow) * 128 + ks * 64 + fgrp * 16) ^ swz;
          const bf16x8 kf = *(const bf16x8*)(Kc + byte);
#pragma unroll
          for (int qs = 0; qs < 4; ++qs)
            sc[qs][tc] = __builtin_amdgcn_mfma_f32_16x16x32_bf16(kf, qf[qs][ks], sc[qs][tc], 0, 0, 0);
        }
      __builtin_amdgcn_s_setprio(0);

      if (kt == nkv - 1) {
        const int kv0 = kt * 128;
#pragma unroll
        for (int qs = 0; qs < 4; ++qs)
#pragma unroll
          for (int tc = 0; tc < 2; ++tc)
#pragma unroll
            for (int r = 0; r < 4; ++r)
              if (kv0 + w32 + tc * 16 + fgrp * 4 + r > q0 + qs * 16 + frow)
                sc[qs][tc][r] = -1e30f;
      }

      bf16x8 pf[4];
#pragma unroll
      for (int qs = 0; qs < 4; ++qs) {
        const float p00 = exp2f(sc[qs][0][0]), p01 = exp2f(sc[qs][0][1]);
        const float p02 = exp2f(sc[qs][0][2]), p03 = exp2f(sc[qs][0][3]);
        const float p10 = exp2f(sc[qs][1][0]), p11 = exp2f(sc[qs][1][1]);
        const float p12 = exp2f(sc[qs][1][2]), p13 = exp2f(sc[qs][1][3]);
        l_lane[qs] += ((p00 + p01) + (p02 + p03)) + ((p10 + p11) + (p12 + p13));
        union { __bf16 bb[2]; uint32_t uu; } c00, c01, c10, c11;
        c00.bb[0] = (__bf16)p00; c00.bb[1] = (__bf16)p01;
        c01.bb[0] = (__bf16)p02; c01.bb[1] = (__bf16)p03;
        c10.bb[0] = (__bf16)p10; c10.bb[1] = (__bf16)p11;
        c11.bb[0] = (__bf16)p12; c11.bb[1] = (__bf16)p13;
        uint32_t a0 = c00.uu, a1 = c01.uu, b0 = c10.uu, b1 = c11.uu;
        plswap32(a0, b0); plswap16(a0, b0);
        plswap32(a1, b1); plswap16(a1, b1);
        union { uint32_t w[4]; bf16x8 v; } pk;
        pk.w[0] = a0; pk.w[1] = a1; pk.w[2] = b0; pk.w[3] = b1;
        pf[qs] = pk.v;
      }

      __builtin_amdgcn_s_setprio(1);
#pragma unroll
      for (int te = 0; te < 4; ++te) {
        const int byte = ((te * 16 + frow) * 256 + wid * 64 + fgrp * 16) ^ swz;
        const bf16x8 vf = *(const bf16x8*)(Vc + byte);
#pragma unroll
        for (int qs = 0; qs < 4; ++qs)
          accO[qs][te] = __builtin_amdgcn_mfma_f32_16x16x32_bf16(pf[qs], vf, accO[qs][te], 0, 0, 0);
      }
      __builtin_amdgcn_s_setprio(0);
      __syncthreads();
    }

    // ---- cross-wave merge (K/V/Q LDS dead; Of rows padded to 68 words) ----
    float* myOf = Of + wid * 4352;  // 68 * 64 rows
#pragma unroll
    for (int qs = 0; qs < 4; ++qs)
#pragma unroll
      for (int te = 0; te < 4; ++te)
#pragma unroll
        for (int r = 0; r < 4; ++r)
          myOf[(qs * 16 + fgrp * 4 + r) * 68 + te * 16 + frow] = accO[qs][te][r];
#pragma unroll
    for (int qs = 0; qs < 4; ++qs) {
      l_lane[qs] += __shfl_xor(l_lane[qs], 16);
      l_lane[qs] += __shfl_xor(l_lane[qs], 32);
    }
    if (fgrp == 0) {
#pragma unroll
      for (int qs = 0; qs < 4; ++qs) Ld[wid * 64 + qs * 16 + frow] = l_lane[qs];
    }
    __syncthreads();

    {
      const int qlb = wid * 16 + fgrp * 4;
#pragma unroll
      for (int i = 0; i < 4; ++i) {
        const int ql = qlb + i;
        f32x4 s = {};
#pragma unroll
        for (int wv = 0; wv < 4; ++wv) {
          const f32x4 t = *(const f32x4*)(Of + wv * 4352 + ql * 68 + frow * 4);
          s += t;
        }
        const float lq = ((Ld[ql] + Ld[64 + ql]) + (Ld[128 + ql] + Ld[192 + ql]));
        const float inv = 1.0f / lq;
        ushort4 o;
        o.x = f2b(s[0] * inv); o.y = f2b(s[1] * inv);
        o.z = f2b(s[2] * inv); o.w = f2b(s[3] * inv);
        *(ushort4*)(attb + base_bh + (size_t)(q0 + ql) * DM + frow * 4) = o;
      }
    }
    __syncthreads();
  }
}

extern "C" void kernel_launch(void* const* d_in, const int* in_sizes, int n_in,
                              void* d_out, int out_size, void* d_ws, size_t ws_size,
                              hipStream_t stream) {
  const float* x  = (const float*)d_in[0];
  const float* wq = (const float*)d_in[1];
  const float* wk = (const float*)d_in[2];
  const float* wv = (const float*)d_in[3];
  const float* wo = (const float*)d_in[4];
  const int* pos  = (const int*)d_in[5];
  float* out = (float*)d_out;
  (void)in_sizes; (void)n_in; (void)out_size; (void)ws_size;

  char* ws = (char*)d_ws;
  const size_t MB = 1024 * 1024;
  u16* xb   = (u16*)(ws);
  u16* wqb  = (u16*)(ws + 8 * MB);
  u16* wkb  = (u16*)(ws + 10 * MB);
  u16* wvb  = (u16*)(ws + 12 * MB);
  u16* wob  = (u16*)(ws + 14 * MB);
  u16* Qb   = (u16*)(ws + 16 * MB);
  u16* Kb   = (u16*)(ws + 24 * MB);
  u16* Vtb  = (u16*)(ws + 32 * MB);   // V^T: [1024][4096]
  u16* attb = (u16*)(ws + 40 * MB);
  float2* tab = (float2*)(ws + 40 * MB);  // aliases attb (dead by attn time)

  cast_all<<<2048, 256, 0, stream>>>(x, wq, wk, wv, wo, pos, xb, wqb, wkb, wvb, wob, tab);
  gemm_proj<<<1024, 256, 0, stream>>>(xb, wqb, wkb, wvb, Qb, Kb, Vtb, tab);
  attn_kernel<<<dim3(16, 32), 256, 0, stream>>>(Qb, Kb, Vtb, attb);
  gemm_o<<<512, 256, 0, stream>>>(attb, wob, out);
}

// Round 25
// 103.727 us; speedup vs baseline: 2.2918x; 1.0776x over previous
//
#include <hip/hip_runtime.h>
#include <hip/hip_bf16.h>
#include <cstdint>
#include <cstddef>

#define DEV static __device__ __forceinline__

typedef __bf16 bf16x8 __attribute__((ext_vector_type(8)));
typedef float f32x4 __attribute__((ext_vector_type(4)));
typedef unsigned short u16;

static constexpr int BATCH = 2, SEQ = 2048, DM = 1024, NH = 16, DH = 64;
static constexpr int Kdim = 1024;
static constexpr int BS = BATCH * SEQ;  // 4096

DEV u16 f2b(float f) {  // f32 -> bf16 RNE
  uint32_t u = __builtin_bit_cast(uint32_t, f);
  u += 0x7FFFu + ((u >> 16) & 1u);
  return (u16)(u >> 16);
}

DEV void gload_lds16(const void* g, void* l) {
  __builtin_amdgcn_global_load_lds((const __attribute__((address_space(1))) void*)g,
                                   (__attribute__((address_space(3))) void*)l, 16, 0, 0);
}

DEV void plswap32(uint32_t& a, uint32_t& b) {
  asm("v_permlane32_swap_b32 %0, %1" : "+v"(a), "+v"(b));
}
DEV void plswap16(uint32_t& a, uint32_t& b) {
  asm("v_permlane16_swap_b32 %0, %1" : "+v"(a), "+v"(b));
}

// raw v_exp_f32: skips the __ocml_exp2_f32 range-fixup (~5 VALU/call).
// Inputs are log2-domain scores (|s| small) or the -1e30 mask -> exp = 0 exact.
#if __has_builtin(__builtin_amdgcn_exp2f)
DEV float fexp2(float x) { return __builtin_amdgcn_exp2f(x); }
#else
DEV float fexp2(float x) { float r; asm("v_exp_f32 %0, %1" : "=v"(r) : "v"(x)); return r; }
#endif

// ---------------- fused cast f32 -> bf16 (x + 4 weights) + RoPE cos/sin table ----------------
__global__ __launch_bounds__(256) void cast_all(const float* __restrict__ x,
    const float* __restrict__ wq, const float* __restrict__ wk,
    const float* __restrict__ wv, const float* __restrict__ wo,
    const int* __restrict__ pos,
    u16* __restrict__ xb, u16* __restrict__ wqb, u16* __restrict__ wkb,
    u16* __restrict__ wvb, u16* __restrict__ wob, float2* __restrict__ tab) {
  const int NX = (BATCH * SEQ * DM) / 4;  // 2097152
  const int NW = (DM * DM) / 4;           // 262144 = 1<<18
  const int NT = SEQ * 32;                // 65536 table entries
  int i = blockIdx.x * blockDim.x + threadIdx.x;
  const int stride = gridDim.x * blockDim.x;
  for (; i < NX + 4 * NW + NT; i += stride) {
    if (i < NX + 4 * NW) {
      const float* src; u16* dst; int off;
      if (i < NX) { src = x; dst = xb; off = i; }
      else {
        const int j = i - NX, seg = j >> 18;
        off = j & (NW - 1);
        src = seg == 0 ? wq : seg == 1 ? wk : seg == 2 ? wv : wo;
        dst = seg == 0 ? wqb : seg == 1 ? wkb : seg == 2 ? wvb : wob;
      }
      float4 v = ((const float4*)src)[off];
      ushort4 o;
      o.x = f2b(v.x); o.y = f2b(v.y); o.z = f2b(v.z); o.w = f2b(v.w);
      ((ushort4*)dst)[off] = o;
    } else {
      const int t = i - NX - 4 * NW;
      const int s = t >> 5, j = t & 31;
      const float ang = (float)pos[s] * exp2f((float)j * -0.4152410118609203f);
      float sn, cs;
      sincosf(ang, &sn, &cs);
      tab[t] = make_float2(cs, sn);
    }
  }
}

// ---------------- generic GEMM core: 128x64, 2-buf, depth-1, counted vmcnt ----------------
template <bool OUTF32>
DEV void gemm_core64(const u16* __restrict__ A, const u16* __restrict__ Bm,
                     void* __restrict__ Cout, int ldC, int m0, int n0,
                     u16* __restrict__ As, u16* __restrict__ Bs) {
  const int tid = threadIdx.x;
  const int lane = tid & 63, wid = tid >> 6;
  const int wr = (wid >> 1) * 64, wc = (wid & 1) * 32;
  const int frow = lane & 15, fgrp = lane >> 4;
  constexpr int NK = Kdim / 32;
  f32x4 acc[4][2] = {};

  const int c0 = tid, c1 = tid + 256;
  const int ra0 = c0 >> 2, sa0 = (c0 & 3) ^ ((ra0 >> 1) & 3);
  const int ra1 = c1 >> 2, sa1 = (c1 & 3) ^ ((ra1 >> 1) & 3);
  const size_t gA0 = (size_t)(m0 + ra0) * Kdim + sa0 * 8;
  const size_t gA1 = (size_t)(m0 + ra1) * Kdim + sa1 * 8;
  const size_t gB0 = (size_t)(n0 + ra0) * Kdim + sa0 * 8;

#define GSTAGE(bufi, kofs)                                                      \
  do {                                                                          \
    gload_lds16(A + gA0 + (kofs), As + (bufi) * 4096 + wid * 512);              \
    gload_lds16(A + gA1 + (kofs), As + (bufi) * 4096 + wid * 512 + 2048);       \
    gload_lds16(Bm + gB0 + (kofs), Bs + (bufi) * 2048 + wid * 512);             \
  } while (0)

  GSTAGE(0, 0);
  for (int kt = 0; kt < NK; ++kt) {
    const int buf = kt & 1;
    if (kt + 1 < NK) {
      GSTAGE((kt + 1) & 1, (kt + 1) * 32);
      asm volatile("s_waitcnt vmcnt(3)" ::: "memory");
    } else {
      asm volatile("s_waitcnt vmcnt(0)" ::: "memory");
    }
    __builtin_amdgcn_s_barrier();

    bf16x8 af[4], bfr[2];
#pragma unroll
    for (int i = 0; i < 4; ++i) {
      const int ra = wr + i * 16 + frow;
      af[i] = *(const bf16x8*)((const char*)(As + buf * 4096) + ra * 64 +
                               ((fgrp ^ ((ra >> 1) & 3)) * 16));
    }
#pragma unroll
    for (int f = 0; f < 2; ++f) {
      const int rb = wc + f * 16 + frow;
      bfr[f] = *(const bf16x8*)((const char*)(Bs + buf * 2048) + rb * 64 +
                                ((fgrp ^ ((rb >> 1) & 3)) * 16));
    }
#pragma unroll
    for (int mi = 0; mi < 4; ++mi)
#pragma unroll
      for (int f = 0; f < 2; ++f)
        acc[mi][f] = __builtin_amdgcn_mfma_f32_16x16x32_bf16(af[mi], bfr[f], acc[mi][f], 0, 0, 0);

    __builtin_amdgcn_s_barrier();
  }
#undef GSTAGE

  const int colb = n0 + wc + frow;
  const int rowb = m0 + wr + fgrp * 4;
#pragma unroll
  for (int mi = 0; mi < 4; ++mi)
#pragma unroll
    for (int f = 0; f < 2; ++f)
#pragma unroll
      for (int r = 0; r < 4; ++r) {
        const int row = rowb + mi * 16 + r;
        const int col = colb + f * 16;
        const float v = acc[mi][f][r];
        if (OUTF32) ((float*)Cout)[(size_t)row * ldC + col] = v;
        else        ((u16*)Cout)[(size_t)row * ldC + col] = f2b(v);
      }
}

// ---------------- fused Q+K core (shares x A-panel; RoPE epilogue) ----------------
DEV void qk_core(const u16* __restrict__ xb, const u16* __restrict__ wq,
                 const u16* __restrict__ wk, u16* __restrict__ Qb, u16* __restrict__ Kb,
                 const float2* __restrict__ tab, int m0, int n0,
                 u16* __restrict__ As, u16* __restrict__ Bq, u16* __restrict__ Bk) {
  const int tid = threadIdx.x;
  const int lane = tid & 63, wid = tid >> 6;
  const int wr = (wid >> 1) * 64, wc = (wid & 1) * 32;
  const int frow = lane & 15, fgrp = lane >> 4;
  constexpr int NK = Kdim / 32;
  f32x4 accQ[4][2] = {}, accK[4][2] = {};

  const int c0 = tid, c1 = tid + 256;
  const int ra0 = c0 >> 2, sa0 = (c0 & 3) ^ ((ra0 >> 1) & 3);
  const int ra1 = c1 >> 2, sa1 = (c1 & 3) ^ ((ra1 >> 1) & 3);
  const size_t gA0 = (size_t)(m0 + ra0) * Kdim + sa0 * 8;
  const size_t gA1 = (size_t)(m0 + ra1) * Kdim + sa1 * 8;
  const size_t gB0 = (size_t)(n0 + ra0) * Kdim + sa0 * 8;

#define QKSTAGE(bufi, kofs)                                                     \
  do {                                                                          \
    gload_lds16(xb + gA0 + (kofs), As + (bufi) * 4096 + wid * 512);             \
    gload_lds16(xb + gA1 + (kofs), As + (bufi) * 4096 + wid * 512 + 2048);      \
    gload_lds16(wq + gB0 + (kofs), Bq + (bufi) * 2048 + wid * 512);             \
    gload_lds16(wk + gB0 + (kofs), Bk + (bufi) * 2048 + wid * 512);             \
  } while (0)

  QKSTAGE(0, 0);
  for (int kt = 0; kt < NK; ++kt) {
    const int buf = kt & 1;
    if (kt + 1 < NK) {
      QKSTAGE((kt + 1) & 1, (kt + 1) * 32);
      asm volatile("s_waitcnt vmcnt(4)" ::: "memory");
    } else {
      asm volatile("s_waitcnt vmcnt(0)" ::: "memory");
    }
    __builtin_amdgcn_s_barrier();

    bf16x8 af[4], bq[2], bk[2];
#pragma unroll
    for (int i = 0; i < 4; ++i) {
      const int ra = wr + i * 16 + frow;
      af[i] = *(const bf16x8*)((const char*)(As + buf * 4096) + ra * 64 +
                               ((fgrp ^ ((ra >> 1) & 3)) * 16));
    }
#pragma unroll
    for (int f2 = 0; f2 < 2; ++f2) {
      const int rb = wc + f2 * 16 + frow;
      const int off = rb * 64 + ((fgrp ^ ((rb >> 1) & 3)) * 16);
      bq[f2] = *(const bf16x8*)((const char*)(Bq + buf * 2048) + off);
      bk[f2] = *(const bf16x8*)((const char*)(Bk + buf * 2048) + off);
    }
#pragma unroll
    for (int mi = 0; mi < 4; ++mi)
#pragma unroll
      for (int f2 = 0; f2 < 2; ++f2) {
        accQ[mi][f2] = __builtin_amdgcn_mfma_f32_16x16x32_bf16(af[mi], bq[f2], accQ[mi][f2], 0, 0, 0);
        accK[mi][f2] = __builtin_amdgcn_mfma_f32_16x16x32_bf16(af[mi], bk[f2], accK[mi][f2], 0, 0, 0);
      }

    __builtin_amdgcn_s_barrier();
  }
#undef QKSTAGE

  const int colb = n0 + wc + frow;
  const int rowb = m0 + wr + fgrp * 4;
#pragma unroll
  for (int mi = 0; mi < 4; ++mi)
#pragma unroll
    for (int f2 = 0; f2 < 2; ++f2) {
      const int col = colb + f2 * 16;
      const int jj = (col & 63) >> 1;
      const int odd = col & 1;
#pragma unroll
      for (int r = 0; r < 4; ++r) {
        const int row = rowb + mi * 16 + r;
        const float2 cs_ = tab[(row & (SEQ - 1)) * 32 + jj];
        const float qv = accQ[mi][f2][r];
        const float qp = __shfl_xor(qv, 1);
        const float kv = accK[mi][f2][r];
        const float kp = __shfl_xor(kv, 1);
        float oq = odd ? fmaf(cs_.y, qp, cs_.x * qv) : fmaf(cs_.x, qv, -cs_.y * qp);
        float ok = odd ? fmaf(cs_.y, kp, cs_.x * kv) : fmaf(cs_.x, kv, -cs_.y * kp);
        oq *= 0.18033688011112043f;  // (1/8)*log2(e), folded into Q
        Qb[(size_t)row * DM + col] = f2b(oq);
        Kb[(size_t)row * DM + col] = f2b(ok);
      }
    }
}

// ---------------- ALL projections in ONE launch (tail overlap) ----------------
// g < 512: fused Q+K tile; g >= 512: V^T tile. XCD locality preserved (g&7).
__global__ __launch_bounds__(256) void gemm_proj(const u16* __restrict__ xb,
    const u16* __restrict__ wq, const u16* __restrict__ wk, const u16* __restrict__ wv,
    u16* __restrict__ Qb, u16* __restrict__ Kb, u16* __restrict__ Vtb,
    const float2* __restrict__ tab) {
  __shared__ u16 As[2][4096], B1[2][2048], B2[2][2048];
  const int g = blockIdx.x;
  if (g < 512) {
    const int xcd = g & 7, j = g >> 3;
    const int m0 = (xcd * 4 + (j >> 4)) * 128, n0 = (j & 15) * 64;
    qk_core(xb, wq, wk, Qb, Kb, tab, m0, n0, &As[0][0], &B1[0][0], &B2[0][0]);
  } else {
    const int f = g - 512;
    const int xcd = f & 7, j = f >> 3;
    const int m0 = xcd * 128, n0 = j * 64;
    gemm_core64<false>(wv, xb, Vtb, BS, m0, n0, &As[0][0], &B1[0][0]);
  }
}

__global__ __launch_bounds__(256) void gemm_o(const u16* __restrict__ attb,
                                              const u16* __restrict__ wob,
                                              float* __restrict__ out) {
  __shared__ u16 As[2][4096], Bs[2][2048];
  const int f = blockIdx.x;                  // 0..511
  const int xcd = f & 7, k = f >> 3;
  const int grp = xcd * 8 + (k >> 3);
  const int m0 = (grp >> 1) * 128;
  const int n0 = ((grp & 1) * 8 + (k & 7)) * 64;
  gemm_core64<true>(attb, wob, out, DM, m0, n0, &As[0][0], &Bs[0][0]);
}

// ---------------- fused causal flash attention (4-wave, measured best: R22) ----------------
// R25 delta: softmax exp2 via raw v_exp_f32 (fexp2) — drops the ocml fixup
// (~5 VALU/call x 32 calls/lane-iter; attn is 51% VALUBusy).
__global__ __launch_bounds__(256, 2) void attn_kernel(const u16* __restrict__ Qb,
                                                      const u16* __restrict__ Kb,
                                                      const u16* __restrict__ Vtb,
                                                      u16* __restrict__ attb) {
  __shared__ __align__(16) unsigned char SM[73728];
  u16* Qs = (u16*)(SM + 65536);
  float* Of = (float*)SM;
  float* Ld = (float*)(SM + 69632);

  const int tid = threadIdx.x, lane = tid & 63, wid = tid >> 6;
  const int flat = (int)blockIdx.x + 16 * (int)blockIdx.y;  // 0..511
  const int orig = (flat & 7) * 64 + (flat >> 3);           // bijective XCD swizzle
  const int xq = orig & 15;
  const int bh = orig >> 4;
  const int b = bh >> 4, h = bh & 15;
  const size_t base_bh = ((size_t)b * SEQ) * DM + h * DH;
  const int frow = lane & 15, fgrp = lane >> 4;
  const int w32 = wid * 32;
  const int swz = (frow & 7) << 4;

  const u16* Ksrcs[4];
  const u16* Vsrcs[4];
#pragma unroll
  for (int i = 0; i < 4; ++i) {
    const int c = tid + i * 256;
    const int rk = c >> 3, s8 = (c & 7) ^ (rk & 7);
    Ksrcs[i] = Kb + base_bh + (size_t)rk * DM + s8 * 8;
    const int rv = c >> 4, s16 = (c & 15) ^ (rv & 7);
    Vsrcs[i] = Vtb + (size_t)(h * DH + rv) * BS + (size_t)b * SEQ + s16 * 8;
  }
  const int cq0 = tid, cq1 = tid + 256;
  const int rq0 = cq0 >> 3, sq0 = (cq0 & 7) ^ (rq0 & 7);
  const int rq1 = cq1 >> 3, sq1 = (cq1 & 7) ^ (rq1 & 7);

#pragma unroll 1
  for (int phase = 0; phase < 2; ++phase) {
    const int qt = phase ? xq : 31 - xq;
    const int q0 = qt * 64;
    const int nkv = (qt >> 1) + 1;

    gload_lds16(Qb + base_bh + (size_t)(q0 + rq0) * DM + sq0 * 8, (char*)SM + 65536 + tid * 16);
    gload_lds16(Qb + base_bh + (size_t)(q0 + rq1) * DM + sq1 * 8, (char*)SM + 69632 + tid * 16);
#pragma unroll
    for (int i = 0; i < 4; ++i) {
      gload_lds16(Ksrcs[i], (char*)SM + wid * 1024 + i * 4096);
      gload_lds16(Vsrcs[i], (char*)SM + 32768 + wid * 1024 + i * 4096);
    }
    __syncthreads();

    bf16x8 qf[4][2];
#pragma unroll
    for (int qs = 0; qs < 4; ++qs)
#pragma unroll
      for (int ks = 0; ks < 2; ++ks) {
        const int byte = ((qs * 16 + frow) * 128 + ks * 64 + fgrp * 16) ^ swz;
        qf[qs][ks] = *(const bf16x8*)((const char*)Qs + byte);
      }

    f32x4 accO[4][4] = {};
    float l_lane[4] = {0.f, 0.f, 0.f, 0.f};

    // strength-reduced prefetch pointers (advance by constant stride per iter)
    const u16* Kp[4];
    const u16* Vp[4];
#pragma unroll
    for (int i = 0; i < 4; ++i) { Kp[i] = Ksrcs[i] + (size_t)128 * DM; Vp[i] = Vsrcs[i] + 128; }

    for (int kt = 0; kt < nkv; ++kt) {
      const char* Kc = (const char*)SM + (kt & 1) * 16384;
      const char* Vc = (const char*)SM + 32768 + (kt & 1) * 16384;
      if (kt + 1 < nkv) {
        const int nb = (kt + 1) & 1;
#pragma unroll
        for (int i = 0; i < 4; ++i) {
          gload_lds16(Kp[i], (char*)SM + nb * 16384 + wid * 1024 + i * 4096);
          gload_lds16(Vp[i], (char*)SM + 32768 + nb * 16384 + wid * 1024 + i * 4096);
          Kp[i] += (size_t)128 * DM;
          Vp[i] += 128;
        }
      }

      f32x4 sc[4][2] = {};
      __builtin_amdgcn_s_setprio(1);
#pragma unroll
      for (int tc = 0; tc < 2; ++tc)
#pragma unroll
        for (int ks = 0; ks < 2; ++ks) {
          const int byte = ((w32 + tc * 16 + frow) * 128 + ks * 64 + fgrp * 16) ^ swz;
          const bf16x8 kf = *(const bf16x8*)(Kc + byte);
#pragma unroll
          for (int qs = 0; qs < 4; ++qs)
            sc[qs][tc] = __builtin_amdgcn_mfma_f32_16x16x32_bf16(kf, qf[qs][ks], sc[qs][tc], 0, 0, 0);
        }
      __builtin_amdgcn_s_setprio(0);

      if (kt == nkv - 1) {
        const int kv0 = kt * 128;
#pragma unroll
        for (int qs = 0; qs < 4; ++qs)
#pragma unroll
          for (int tc = 0; tc < 2; ++tc)
#pragma unroll
            for (int r = 0; r < 4; ++r)
              if (kv0 + w32 + tc * 16 + fgrp * 4 + r > q0 + qs * 16 + frow)
                sc[qs][tc][r] = -1e30f;
      }

      bf16x8 pf[4];
#pragma unroll
      for (int qs = 0; qs < 4; ++qs) {
        const float p00 = fexp2(sc[qs][0][0]), p01 = fexp2(sc[qs][0][1]);
        const float p02 = fexp2(sc[qs][0][2]), p03 = fexp2(sc[qs][0][3]);
        const float p10 = fexp2(sc[qs][1][0]), p11 = fexp2(sc[qs][1][1]);
        const float p12 = fexp2(sc[qs][1][2]), p13 = fexp2(sc[qs][1][3]);
        l_lane[qs] += ((p00 + p01) + (p02 + p03)) + ((p10 + p11) + (p12 + p13));
        union { __bf16 bb[2]; uint32_t uu; } c00, c01, c10, c11;
        c00.bb[0] = (__bf16)p00; c00.bb[1] = (__bf16)p01;
        c01.bb[0] = (__bf16)p02; c01.bb[1] = (__bf16)p03;
        c10.bb[0] = (__bf16)p10; c10.bb[1] = (__bf16)p11;
        c11.bb[0] = (__bf16)p12; c11.bb[1] = (__bf16)p13;
        uint32_t a0 = c00.uu, a1 = c01.uu, b0 = c10.uu, b1 = c11.uu;
        plswap32(a0, b0); plswap16(a0, b0);
        plswap32(a1, b1); plswap16(a1, b1);
        union { uint32_t w[4]; bf16x8 v; } pk;
        pk.w[0] = a0; pk.w[1] = a1; pk.w[2] = b0; pk.w[3] = b1;
        pf[qs] = pk.v;
      }

      __builtin_amdgcn_s_setprio(1);
#pragma unroll
      for (int te = 0; te < 4; ++te) {
        const int byte = ((te * 16 + frow) * 256 + wid * 64 + fgrp * 16) ^ swz;
        const bf16x8 vf = *(const bf16x8*)(Vc + byte);
#pragma unroll
        for (int qs = 0; qs < 4; ++qs)
          accO[qs][te] = __builtin_amdgcn_mfma_f32_16x16x32_bf16(pf[qs], vf, accO[qs][te], 0, 0, 0);
      }
      __builtin_amdgcn_s_setprio(0);
      __syncthreads();
    }

    // ---- cross-wave merge (K/V/Q LDS dead; Of rows padded to 68 words) ----
    float* myOf = Of + wid * 4352;  // 68 * 64 rows
#pragma unroll
    for (int qs = 0; qs < 4; ++qs)
#pragma unroll
      for (int te = 0; te < 4; ++te)
#pragma unroll
        for (int r = 0; r < 4; ++r)
          myOf[(qs * 16 + fgrp * 4 + r) * 68 + te * 16 + frow] = accO[qs][te][r];
#pragma unroll
    for (int qs = 0; qs < 4; ++qs) {
      l_lane[qs] += __shfl_xor(l_lane[qs], 16);
      l_lane[qs] += __shfl_xor(l_lane[qs], 32);
    }
    if (fgrp == 0) {
#pragma unroll
      for (int qs = 0; qs < 4; ++qs) Ld[wid * 64 + qs * 16 + frow] = l_lane[qs];
    }
    __syncthreads();

    {
      const int qlb = wid * 16 + fgrp * 4;
#pragma unroll
      for (int i = 0; i < 4; ++i) {
        const int ql = qlb + i;
        f32x4 s = {};
#pragma unroll
        for (int wv = 0; wv < 4; ++wv) {
          const f32x4 t = *(const f32x4*)(Of + wv * 4352 + ql * 68 + frow * 4);
          s += t;
        }
        const float lq = ((Ld[ql] + Ld[64 + ql]) + (Ld[128 + ql] + Ld[192 + ql]));
        const float inv = 1.0f / lq;
        ushort4 o;
        o.x = f2b(s[0] * inv); o.y = f2b(s[1] * inv);
        o.z = f2b(s[2] * inv); o.w = f2b(s[3] * inv);
        *(ushort4*)(attb + base_bh + (size_t)(q0 + ql) * DM + frow * 4) = o;
      }
    }
    __syncthreads();
  }
}

extern "C" void kernel_launch(void* const* d_in, const int* in_sizes, int n_in,
                              void* d_out, int out_size, void* d_ws, size_t ws_size,
                              hipStream_t stream) {
  const float* x  = (const float*)d_in[0];
  const float* wq = (const float*)d_in[1];
  const float* wk = (const float*)d_in[2];
  const float* wv = (const float*)d_in[3];
  const float* wo = (const float*)d_in[4];
  const int* pos  = (const int*)d_in[5];
  float* out = (float*)d_out;
  (void)in_sizes; (void)n_in; (void)out_size; (void)ws_size;

  char* ws = (char*)d_ws;
  const size_t MB = 1024 * 1024;
  u16* xb   = (u16*)(ws);
  u16* wqb  = (u16*)(ws + 8 * MB);
  u16* wkb  = (u16*)(ws + 10 * MB);
  u16* wvb  = (u16*)(ws + 12 * MB);
  u16* wob  = (u16*)(ws + 14 * MB);
  u16* Qb   = (u16*)(ws + 16 * MB);
  u16* Kb   = (u16*)(ws + 24 * MB);
  u16* Vtb  = (u16*)(ws + 32 * MB);   // V^T: [1024][4096]
  u16* attb = (u16*)(ws + 40 * MB);
  float2* tab = (float2*)(ws + 40 * MB);  // aliases attb (dead by attn time)

  cast_all<<<2048, 256, 0, stream>>>(x, wq, wk, wv, wo, pos, xb, wqb, wkb, wvb, wob, tab);
  gemm_proj<<<1024, 256, 0, stream>>>(xb, wqb, wkb, wvb, Qb, Kb, Vtb, tab);
  attn_kernel<<<dim3(16, 32), 256, 0, stream>>>(Qb, Kb, Vtb, attb);
  gemm_o<<<512, 256, 0, stream>>>(attb, wob, out);
}

// Round 26
// 102.916 us; speedup vs baseline: 2.3098x; 1.0079x over previous
//
#include <hip/hip_runtime.h>
#include <hip/hip_bf16.h>
#include <cstdint>
#include <cstddef>

#define DEV static __device__ __forceinline__

typedef __bf16 bf16x8 __attribute__((ext_vector_type(8)));
typedef float f32x4 __attribute__((ext_vector_type(4)));
typedef unsigned short u16;

static constexpr int BATCH = 2, SEQ = 2048, DM = 1024, NH = 16, DH = 64;
static constexpr int Kdim = 1024;
static constexpr int BS = BATCH * SEQ;  // 4096

DEV u16 f2b(float f) {  // f32 -> bf16 RNE
  uint32_t u = __builtin_bit_cast(uint32_t, f);
  u += 0x7FFFu + ((u >> 16) & 1u);
  return (u16)(u >> 16);
}

DEV void gload_lds16(const void* g, void* l) {
  __builtin_amdgcn_global_load_lds((const __attribute__((address_space(1))) void*)g,
                                   (__attribute__((address_space(3))) void*)l, 16, 0, 0);
}

DEV void plswap32(uint32_t& a, uint32_t& b) {
  asm("v_permlane32_swap_b32 %0, %1" : "+v"(a), "+v"(b));
}
DEV void plswap16(uint32_t& a, uint32_t& b) {
  asm("v_permlane16_swap_b32 %0, %1" : "+v"(a), "+v"(b));
}

// raw v_exp_f32: skips the __ocml_exp2_f32 range-fixup (~5 VALU/call).
// Inputs are log2-domain scores (|s| small) or the -1e30 mask -> exp = 0 exact.
#if __has_builtin(__builtin_amdgcn_exp2f)
DEV float fexp2(float x) { return __builtin_amdgcn_exp2f(x); }
#else
DEV float fexp2(float x) { float r; asm("v_exp_f32 %0, %1" : "=v"(r) : "v"(x)); return r; }
#endif

// ---------------- fused cast f32 -> bf16 (x + 4 weights) + RoPE cos/sin table ----------------
__global__ __launch_bounds__(256) void cast_all(const float* __restrict__ x,
    const float* __restrict__ wq, const float* __restrict__ wk,
    const float* __restrict__ wv, const float* __restrict__ wo,
    const int* __restrict__ pos,
    u16* __restrict__ xb, u16* __restrict__ wqb, u16* __restrict__ wkb,
    u16* __restrict__ wvb, u16* __restrict__ wob, float2* __restrict__ tab) {
  const int NX = (BATCH * SEQ * DM) / 4;  // 2097152
  const int NW = (DM * DM) / 4;           // 262144 = 1<<18
  const int NT = SEQ * 32;                // 65536 table entries
  int i = blockIdx.x * blockDim.x + threadIdx.x;
  const int stride = gridDim.x * blockDim.x;
  for (; i < NX + 4 * NW + NT; i += stride) {
    if (i < NX + 4 * NW) {
      const float* src; u16* dst; int off;
      if (i < NX) { src = x; dst = xb; off = i; }
      else {
        const int j = i - NX, seg = j >> 18;
        off = j & (NW - 1);
        src = seg == 0 ? wq : seg == 1 ? wk : seg == 2 ? wv : wo;
        dst = seg == 0 ? wqb : seg == 1 ? wkb : seg == 2 ? wvb : wob;
      }
      float4 v = ((const float4*)src)[off];
      ushort4 o;
      o.x = f2b(v.x); o.y = f2b(v.y); o.z = f2b(v.z); o.w = f2b(v.w);
      ((ushort4*)dst)[off] = o;
    } else {
      const int t = i - NX - 4 * NW;
      const int s = t >> 5, j = t & 31;
      const float ang = (float)pos[s] * exp2f((float)j * -0.4152410118609203f);
      float sn, cs;
      sincosf(ang, &sn, &cs);
      tab[t] = make_float2(cs, sn);
    }
  }
}

// ---------------- generic GEMM core: 128x64, 2-buf, depth-1, counted vmcnt ----------------
template <bool OUTF32>
DEV void gemm_core64(const u16* __restrict__ A, const u16* __restrict__ Bm,
                     void* __restrict__ Cout, int ldC, int m0, int n0,
                     u16* __restrict__ As, u16* __restrict__ Bs) {
  const int tid = threadIdx.x;
  const int lane = tid & 63, wid = tid >> 6;
  const int wr = (wid >> 1) * 64, wc = (wid & 1) * 32;
  const int frow = lane & 15, fgrp = lane >> 4;
  constexpr int NK = Kdim / 32;
  f32x4 acc[4][2] = {};

  const int c0 = tid, c1 = tid + 256;
  const int ra0 = c0 >> 2, sa0 = (c0 & 3) ^ ((ra0 >> 1) & 3);
  const int ra1 = c1 >> 2, sa1 = (c1 & 3) ^ ((ra1 >> 1) & 3);
  const size_t gA0 = (size_t)(m0 + ra0) * Kdim + sa0 * 8;
  const size_t gA1 = (size_t)(m0 + ra1) * Kdim + sa1 * 8;
  const size_t gB0 = (size_t)(n0 + ra0) * Kdim + sa0 * 8;

#define GSTAGE(bufi, kofs)                                                      \
  do {                                                                          \
    gload_lds16(A + gA0 + (kofs), As + (bufi) * 4096 + wid * 512);              \
    gload_lds16(A + gA1 + (kofs), As + (bufi) * 4096 + wid * 512 + 2048);       \
    gload_lds16(Bm + gB0 + (kofs), Bs + (bufi) * 2048 + wid * 512);             \
  } while (0)

  GSTAGE(0, 0);
  for (int kt = 0; kt < NK; ++kt) {
    const int buf = kt & 1;
    if (kt + 1 < NK) {
      GSTAGE((kt + 1) & 1, (kt + 1) * 32);
      asm volatile("s_waitcnt vmcnt(3)" ::: "memory");
    } else {
      asm volatile("s_waitcnt vmcnt(0)" ::: "memory");
    }
    __builtin_amdgcn_s_barrier();

    bf16x8 af[4], bfr[2];
#pragma unroll
    for (int i = 0; i < 4; ++i) {
      const int ra = wr + i * 16 + frow;
      af[i] = *(const bf16x8*)((const char*)(As + buf * 4096) + ra * 64 +
                               ((fgrp ^ ((ra >> 1) & 3)) * 16));
    }
#pragma unroll
    for (int f = 0; f < 2; ++f) {
      const int rb = wc + f * 16 + frow;
      bfr[f] = *(const bf16x8*)((const char*)(Bs + buf * 2048) + rb * 64 +
                                ((fgrp ^ ((rb >> 1) & 3)) * 16));
    }
#pragma unroll
    for (int mi = 0; mi < 4; ++mi)
#pragma unroll
      for (int f = 0; f < 2; ++f)
        acc[mi][f] = __builtin_amdgcn_mfma_f32_16x16x32_bf16(af[mi], bfr[f], acc[mi][f], 0, 0, 0);

    __builtin_amdgcn_s_barrier();
  }
#undef GSTAGE

  const int colb = n0 + wc + frow;
  const int rowb = m0 + wr + fgrp * 4;
#pragma unroll
  for (int mi = 0; mi < 4; ++mi)
#pragma unroll
    for (int f = 0; f < 2; ++f)
#pragma unroll
      for (int r = 0; r < 4; ++r) {
        const int row = rowb + mi * 16 + r;
        const int col = colb + f * 16;
        const float v = acc[mi][f][r];
        if (OUTF32) ((float*)Cout)[(size_t)row * ldC + col] = v;
        else        ((u16*)Cout)[(size_t)row * ldC + col] = f2b(v);
      }
}

// ---------------- fused Q+K core (shares x A-panel; RoPE epilogue) ----------------
DEV void qk_core(const u16* __restrict__ xb, const u16* __restrict__ wq,
                 const u16* __restrict__ wk, u16* __restrict__ Qb, u16* __restrict__ Kb,
                 const float2* __restrict__ tab, int m0, int n0,
                 u16* __restrict__ As, u16* __restrict__ Bq, u16* __restrict__ Bk) {
  const int tid = threadIdx.x;
  const int lane = tid & 63, wid = tid >> 6;
  const int wr = (wid >> 1) * 64, wc = (wid & 1) * 32;
  const int frow = lane & 15, fgrp = lane >> 4;
  constexpr int NK = Kdim / 32;
  f32x4 accQ[4][2] = {}, accK[4][2] = {};

  const int c0 = tid, c1 = tid + 256;
  const int ra0 = c0 >> 2, sa0 = (c0 & 3) ^ ((ra0 >> 1) & 3);
  const int ra1 = c1 >> 2, sa1 = (c1 & 3) ^ ((ra1 >> 1) & 3);
  const size_t gA0 = (size_t)(m0 + ra0) * Kdim + sa0 * 8;
  const size_t gA1 = (size_t)(m0 + ra1) * Kdim + sa1 * 8;
  const size_t gB0 = (size_t)(n0 + ra0) * Kdim + sa0 * 8;

#define QKSTAGE(bufi, kofs)                                                     \
  do {                                                                          \
    gload_lds16(xb + gA0 + (kofs), As + (bufi) * 4096 + wid * 512);             \
    gload_lds16(xb + gA1 + (kofs), As + (bufi) * 4096 + wid * 512 + 2048);      \
    gload_lds16(wq + gB0 + (kofs), Bq + (bufi) * 2048 + wid * 512);             \
    gload_lds16(wk + gB0 + (kofs), Bk + (bufi) * 2048 + wid * 512);             \
  } while (0)

  QKSTAGE(0, 0);
  for (int kt = 0; kt < NK; ++kt) {
    const int buf = kt & 1;
    if (kt + 1 < NK) {
      QKSTAGE((kt + 1) & 1, (kt + 1) * 32);
      asm volatile("s_waitcnt vmcnt(4)" ::: "memory");
    } else {
      asm volatile("s_waitcnt vmcnt(0)" ::: "memory");
    }
    __builtin_amdgcn_s_barrier();

    bf16x8 af[4], bq[2], bk[2];
#pragma unroll
    for (int i = 0; i < 4; ++i) {
      const int ra = wr + i * 16 + frow;
      af[i] = *(const bf16x8*)((const char*)(As + buf * 4096) + ra * 64 +
                               ((fgrp ^ ((ra >> 1) & 3)) * 16));
    }
#pragma unroll
    for (int f2 = 0; f2 < 2; ++f2) {
      const int rb = wc + f2 * 16 + frow;
      const int off = rb * 64 + ((fgrp ^ ((rb >> 1) & 3)) * 16);
      bq[f2] = *(const bf16x8*)((const char*)(Bq + buf * 2048) + off);
      bk[f2] = *(const bf16x8*)((const char*)(Bk + buf * 2048) + off);
    }
#pragma unroll
    for (int mi = 0; mi < 4; ++mi)
#pragma unroll
      for (int f2 = 0; f2 < 2; ++f2) {
        accQ[mi][f2] = __builtin_amdgcn_mfma_f32_16x16x32_bf16(af[mi], bq[f2], accQ[mi][f2], 0, 0, 0);
        accK[mi][f2] = __builtin_amdgcn_mfma_f32_16x16x32_bf16(af[mi], bk[f2], accK[mi][f2], 0, 0, 0);
      }

    __builtin_amdgcn_s_barrier();
  }
#undef QKSTAGE

  const int colb = n0 + wc + frow;
  const int rowb = m0 + wr + fgrp * 4;
#pragma unroll
  for (int mi = 0; mi < 4; ++mi)
#pragma unroll
    for (int f2 = 0; f2 < 2; ++f2) {
      const int col = colb + f2 * 16;
      const int jj = (col & 63) >> 1;
      const int odd = col & 1;
#pragma unroll
      for (int r = 0; r < 4; ++r) {
        const int row = rowb + mi * 16 + r;
        const float2 cs_ = tab[(row & (SEQ - 1)) * 32 + jj];
        const float qv = accQ[mi][f2][r];
        const float qp = __shfl_xor(qv, 1);
        const float kv = accK[mi][f2][r];
        const float kp = __shfl_xor(kv, 1);
        float oq = odd ? fmaf(cs_.y, qp, cs_.x * qv) : fmaf(cs_.x, qv, -cs_.y * qp);
        float ok = odd ? fmaf(cs_.y, kp, cs_.x * kv) : fmaf(cs_.x, kv, -cs_.y * kp);
        oq *= 0.18033688011112043f;  // (1/8)*log2(e), folded into Q
        Qb[(size_t)row * DM + col] = f2b(oq);
        Kb[(size_t)row * DM + col] = f2b(ok);
      }
    }
}

// ---------------- ALL projections in ONE launch (tail overlap) ----------------
// g < 512: fused Q+K tile; g >= 512: V^T tile. XCD locality preserved (g&7).
__global__ __launch_bounds__(256) void gemm_proj(const u16* __restrict__ xb,
    const u16* __restrict__ wq, const u16* __restrict__ wk, const u16* __restrict__ wv,
    u16* __restrict__ Qb, u16* __restrict__ Kb, u16* __restrict__ Vtb,
    const float2* __restrict__ tab) {
  __shared__ u16 As[2][4096], B1[2][2048], B2[2][2048];
  const int g = blockIdx.x;
  if (g < 512) {
    const int xcd = g & 7, j = g >> 3;
    const int m0 = (xcd * 4 + (j >> 4)) * 128, n0 = (j & 15) * 64;
    qk_core(xb, wq, wk, Qb, Kb, tab, m0, n0, &As[0][0], &B1[0][0], &B2[0][0]);
  } else {
    const int f = g - 512;
    const int xcd = f & 7, j = f >> 3;
    const int m0 = xcd * 128, n0 = j * 64;
    gemm_core64<false>(wv, xb, Vtb, BS, m0, n0, &As[0][0], &B1[0][0]);
  }
}

__global__ __launch_bounds__(256) void gemm_o(const u16* __restrict__ attb,
                                              const u16* __restrict__ wob,
                                              float* __restrict__ out) {
  __shared__ u16 As[2][4096], Bs[2][2048];
  const int f = blockIdx.x;                  // 0..511
  const int xcd = f & 7, k = f >> 3;
  const int grp = xcd * 8 + (k >> 3);
  const int m0 = (grp >> 1) * 128;
  const int n0 = ((grp & 1) * 8 + (k & 7)) * 64;
  gemm_core64<true>(attb, wob, out, DM, m0, n0, &As[0][0], &Bs[0][0]);
}

// ---------------- fused causal flash attention (4-wave, measured best) ----------------
// R26 delta: l computed by MFMA against an all-ones B fragment (accL) —
// removes the 32 fp32 adds/lane-iter and the epilogue cross-lane shuffles.
// accL layout = accO layout (row=q, cols replicated), so lanes frow==0 hold
// l[q = qs*16 + fgrp*4 + r] — written directly to Ld.
__global__ __launch_bounds__(256, 2) void attn_kernel(const u16* __restrict__ Qb,
                                                      const u16* __restrict__ Kb,
                                                      const u16* __restrict__ Vtb,
                                                      u16* __restrict__ attb) {
  __shared__ __align__(16) unsigned char SM[73728];
  u16* Qs = (u16*)(SM + 65536);
  float* Of = (float*)SM;
  float* Ld = (float*)(SM + 69632);

  const int tid = threadIdx.x, lane = tid & 63, wid = tid >> 6;
  const int flat = (int)blockIdx.x + 16 * (int)blockIdx.y;  // 0..511
  const int orig = (flat & 7) * 64 + (flat >> 3);           // bijective XCD swizzle
  const int xq = orig & 15;
  const int bh = orig >> 4;
  const int b = bh >> 4, h = bh & 15;
  const size_t base_bh = ((size_t)b * SEQ) * DM + h * DH;
  const int frow = lane & 15, fgrp = lane >> 4;
  const int w32 = wid * 32;
  const int swz = (frow & 7) << 4;

  union { __bf16 bb[8]; bf16x8 v; } onesu;
#pragma unroll
  for (int i = 0; i < 8; ++i) onesu.bb[i] = (__bf16)1.0f;
  const bf16x8 vones = onesu.v;

  const u16* Ksrcs[4];
  const u16* Vsrcs[4];
#pragma unroll
  for (int i = 0; i < 4; ++i) {
    const int c = tid + i * 256;
    const int rk = c >> 3, s8 = (c & 7) ^ (rk & 7);
    Ksrcs[i] = Kb + base_bh + (size_t)rk * DM + s8 * 8;
    const int rv = c >> 4, s16 = (c & 15) ^ (rv & 7);
    Vsrcs[i] = Vtb + (size_t)(h * DH + rv) * BS + (size_t)b * SEQ + s16 * 8;
  }
  const int cq0 = tid, cq1 = tid + 256;
  const int rq0 = cq0 >> 3, sq0 = (cq0 & 7) ^ (rq0 & 7);
  const int rq1 = cq1 >> 3, sq1 = (cq1 & 7) ^ (rq1 & 7);

#pragma unroll 1
  for (int phase = 0; phase < 2; ++phase) {
    const int qt = phase ? xq : 31 - xq;
    const int q0 = qt * 64;
    const int nkv = (qt >> 1) + 1;

    gload_lds16(Qb + base_bh + (size_t)(q0 + rq0) * DM + sq0 * 8, (char*)SM + 65536 + tid * 16);
    gload_lds16(Qb + base_bh + (size_t)(q0 + rq1) * DM + sq1 * 8, (char*)SM + 69632 + tid * 16);
#pragma unroll
    for (int i = 0; i < 4; ++i) {
      gload_lds16(Ksrcs[i], (char*)SM + wid * 1024 + i * 4096);
      gload_lds16(Vsrcs[i], (char*)SM + 32768 + wid * 1024 + i * 4096);
    }
    __syncthreads();

    bf16x8 qf[4][2];
#pragma unroll
    for (int qs = 0; qs < 4; ++qs)
#pragma unroll
      for (int ks = 0; ks < 2; ++ks) {
        const int byte = ((qs * 16 + frow) * 128 + ks * 64 + fgrp * 16) ^ swz;
        qf[qs][ks] = *(const bf16x8*)((const char*)Qs + byte);
      }

    f32x4 accO[4][4] = {};
    f32x4 accL[4] = {};

    // strength-reduced prefetch pointers (advance by constant stride per iter)
    const u16* Kp[4];
    const u16* Vp[4];
#pragma unroll
    for (int i = 0; i < 4; ++i) { Kp[i] = Ksrcs[i] + (size_t)128 * DM; Vp[i] = Vsrcs[i] + 128; }

    for (int kt = 0; kt < nkv; ++kt) {
      const char* Kc = (const char*)SM + (kt & 1) * 16384;
      const char* Vc = (const char*)SM + 32768 + (kt & 1) * 16384;
      if (kt + 1 < nkv) {
        const int nb = (kt + 1) & 1;
#pragma unroll
        for (int i = 0; i < 4; ++i) {
          gload_lds16(Kp[i], (char*)SM + nb * 16384 + wid * 1024 + i * 4096);
          gload_lds16(Vp[i], (char*)SM + 32768 + nb * 16384 + wid * 1024 + i * 4096);
          Kp[i] += (size_t)128 * DM;
          Vp[i] += 128;
        }
      }

      f32x4 sc[4][2] = {};
      __builtin_amdgcn_s_setprio(1);
#pragma unroll
      for (int tc = 0; tc < 2; ++tc)
#pragma unroll
        for (int ks = 0; ks < 2; ++ks) {
          const int byte = ((w32 + tc * 16 + frow) * 128 + ks * 64 + fgrp * 16) ^ swz;
          const bf16x8 kf = *(const bf16x8*)(Kc + byte);
#pragma unroll
          for (int qs = 0; qs < 4; ++qs)
            sc[qs][tc] = __builtin_amdgcn_mfma_f32_16x16x32_bf16(kf, qf[qs][ks], sc[qs][tc], 0, 0, 0);
        }
      __builtin_amdgcn_s_setprio(0);

      if (kt == nkv - 1) {
        const int kv0 = kt * 128;
#pragma unroll
        for (int qs = 0; qs < 4; ++qs)
#pragma unroll
          for (int tc = 0; tc < 2; ++tc)
#pragma unroll
            for (int r = 0; r < 4; ++r)
              if (kv0 + w32 + tc * 16 + fgrp * 4 + r > q0 + qs * 16 + frow)
                sc[qs][tc][r] = -1e30f;
      }

      bf16x8 pf[4];
#pragma unroll
      for (int qs = 0; qs < 4; ++qs) {
        const float p00 = fexp2(sc[qs][0][0]), p01 = fexp2(sc[qs][0][1]);
        const float p02 = fexp2(sc[qs][0][2]), p03 = fexp2(sc[qs][0][3]);
        const float p10 = fexp2(sc[qs][1][0]), p11 = fexp2(sc[qs][1][1]);
        const float p12 = fexp2(sc[qs][1][2]), p13 = fexp2(sc[qs][1][3]);
        union { __bf16 bb[2]; uint32_t uu; } c00, c01, c10, c11;
        c00.bb[0] = (__bf16)p00; c00.bb[1] = (__bf16)p01;
        c01.bb[0] = (__bf16)p02; c01.bb[1] = (__bf16)p03;
        c10.bb[0] = (__bf16)p10; c10.bb[1] = (__bf16)p11;
        c11.bb[0] = (__bf16)p12; c11.bb[1] = (__bf16)p13;
        uint32_t a0 = c00.uu, a1 = c01.uu, b0 = c10.uu, b1 = c11.uu;
        plswap32(a0, b0); plswap16(a0, b0);
        plswap32(a1, b1); plswap16(a1, b1);
        union { uint32_t w[4]; bf16x8 v; } pk;
        pk.w[0] = a0; pk.w[1] = a1; pk.w[2] = b0; pk.w[3] = b1;
        pf[qs] = pk.v;
      }

      __builtin_amdgcn_s_setprio(1);
#pragma unroll
      for (int te = 0; te < 4; ++te) {
        const int byte = ((te * 16 + frow) * 256 + wid * 64 + fgrp * 16) ^ swz;
        const bf16x8 vf = *(const bf16x8*)(Vc + byte);
#pragma unroll
        for (int qs = 0; qs < 4; ++qs)
          accO[qs][te] = __builtin_amdgcn_mfma_f32_16x16x32_bf16(pf[qs], vf, accO[qs][te], 0, 0, 0);
      }
#pragma unroll
      for (int qs = 0; qs < 4; ++qs)
        accL[qs] = __builtin_amdgcn_mfma_f32_16x16x32_bf16(pf[qs], vones, accL[qs], 0, 0, 0);
      __builtin_amdgcn_s_setprio(0);
      __syncthreads();
    }

    // ---- cross-wave merge (K/V/Q LDS dead; Of rows padded to 68 words) ----
    float* myOf = Of + wid * 4352;  // 68 * 64 rows
#pragma unroll
    for (int qs = 0; qs < 4; ++qs)
#pragma unroll
      for (int te = 0; te < 4; ++te)
#pragma unroll
        for (int r = 0; r < 4; ++r)
          myOf[(qs * 16 + fgrp * 4 + r) * 68 + te * 16 + frow] = accO[qs][te][r];
    if (frow == 0) {
#pragma unroll
      for (int qs = 0; qs < 4; ++qs)
#pragma unroll
        for (int r = 0; r < 4; ++r)
          Ld[wid * 64 + qs * 16 + fgrp * 4 + r] = accL[qs][r];
    }
    __syncthreads();

    {
      const int qlb = wid * 16 + fgrp * 4;
#pragma unroll
      for (int i = 0; i < 4; ++i) {
        const int ql = qlb + i;
        f32x4 s = {};
#pragma unroll
        for (int wv = 0; wv < 4; ++wv) {
          const f32x4 t = *(const f32x4*)(Of + wv * 4352 + ql * 68 + frow * 4);
          s += t;
        }
        const float lq = ((Ld[ql] + Ld[64 + ql]) + (Ld[128 + ql] + Ld[192 + ql]));
        const float inv = 1.0f / lq;
        ushort4 o;
        o.x = f2b(s[0] * inv); o.y = f2b(s[1] * inv);
        o.z = f2b(s[2] * inv); o.w = f2b(s[3] * inv);
        *(ushort4*)(attb + base_bh + (size_t)(q0 + ql) * DM + frow * 4) = o;
      }
    }
    __syncthreads();
  }
}

extern "C" void kernel_launch(void* const* d_in, const int* in_sizes, int n_in,
                              void* d_out, int out_size, void* d_ws, size_t ws_size,
                              hipStream_t stream) {
  const float* x  = (const float*)d_in[0];
  const float* wq = (const float*)d_in[1];
  const float* wk = (const float*)d_in[2];
  const float* wv = (const float*)d_in[3];
  const float* wo = (const float*)d_in[4];
  const int* pos  = (const int*)d_in[5];
  float* out = (float*)d_out;
  (void)in_sizes; (void)n_in; (void)out_size; (void)ws_size;

  char* ws = (char*)d_ws;
  const size_t MB = 1024 * 1024;
  u16* xb   = (u16*)(ws);
  u16* wqb  = (u16*)(ws + 8 * MB);
  u16* wkb  = (u16*)(ws + 10 * MB);
  u16* wvb  = (u16*)(ws + 12 * MB);
  u16* wob  = (u16*)(ws + 14 * MB);
  u16* Qb   = (u16*)(ws + 16 * MB);
  u16* Kb   = (u16*)(ws + 24 * MB);
  u16* Vtb  = (u16*)(ws + 32 * MB);   // V^T: [1024][4096]
  u16* attb = (u16*)(ws + 40 * MB);
  float2* tab = (float2*)(ws + 40 * MB);  // aliases attb (dead by attn time)

  cast_all<<<2048, 256, 0, stream>>>(x, wq, wk, wv, wo, pos, xb, wqb, wkb, wvb, wob, tab);
  gemm_proj<<<1024, 256, 0, stream>>>(xb, wqb, wkb, wvb, Qb, Kb, Vtb, tab);
  attn_kernel<<<dim3(16, 32), 256, 0, stream>>>(Qb, Kb, Vtb, attb);
  gemm_o<<<512, 256, 0, stream>>>(attb, wob, out);
}